// Round 8
// baseline (245.660 us; speedup 1.0000x reference)
//
#include <hip/hip_runtime.h>

#define N_NODES 50000
#define N_EDGES 320000
#define IN_FEAT 128
#define HIDDEN  256
#define NCLS    40
#define BN_EPS  1e-5f

#define SCAN_B  256
#define SCAN_NB ((N_NODES + SCAN_B - 1) / SCAN_B)   // 196
#define GNB     (N_NODES / 16)                      // 3125 blocks, 16 nodes each

// prep kernel partition
#define PREP_HIST_NB  (N_EDGES / 256)               // 1250
#define PREP_CVT_NB   (N_NODES * IN_FEAT / 8 / 256) // 3125
#define PREP_PACK_NB  54                            // 216 wave-units / 4
#define BNA_NB        (N_NODES * HIDDEN / 8 / 256)  // 6250

typedef __attribute__((ext_vector_type(8))) _Float16 f16x8;
typedef __attribute__((ext_vector_type(2))) _Float16 f16x2;
typedef __attribute__((ext_vector_type(4))) float f32x4;

__device__ __forceinline__ f16x2 pkmax0(f16x2 a) {
    return __builtin_elementwise_max(a, (f16x2)(_Float16)0.f);
}

__device__ __forceinline__ void packB_unit(const float* __restrict__ W,
                                           _Float16* __restrict__ Bp,
                                           int nt, int kt, int nkt, int M, int lane) {
    const int n = nt * 16 + (lane & 15);
    const int kb = kt * 32 + (lane >> 4) * 8;
    _Float16* dst = Bp + (((size_t)nt * nkt + kt) * 64 + lane) * 8;
#pragma unroll
    for (int j = 0; j < 8; j++)
        dst[j] = (n < M) ? (_Float16)W[(size_t)(kb + j) * M + n] : (_Float16)0.f;
}

// ---------------- merged prep: hist + x cast + W packs ----------------
__global__ __launch_bounds__(256) void k_prep(const int* __restrict__ e_dst,
                                              int* __restrict__ counts,
                                              const float* __restrict__ x,
                                              _Float16* __restrict__ Xh,
                                              const float* __restrict__ W1,
                                              const float* __restrict__ W2,
                                              const float* __restrict__ W3,
                                              _Float16* __restrict__ W1p,
                                              _Float16* __restrict__ W2p,
                                              _Float16* __restrict__ W3p) {
    const int b = blockIdx.x;
    const int tid = threadIdx.x;
    if (b < PREP_HIST_NB) {
        const int e = b * 256 + tid;                  // 1250*256 == N_EDGES
        atomicAdd(&counts[e_dst[e]], 1);
    } else if (b < PREP_HIST_NB + PREP_CVT_NB) {
        const int i = (b - PREP_HIST_NB) * 256 + tid; // exact cover
        float4 a = *(const float4*)(x + (size_t)i * 8);
        float4 c = *(const float4*)(x + (size_t)i * 8 + 4);
        f16x8 o = {(_Float16)a.x, (_Float16)a.y, (_Float16)a.z, (_Float16)a.w,
                   (_Float16)c.x, (_Float16)c.y, (_Float16)c.z, (_Float16)c.w};
        *(f16x8*)&Xh[(size_t)i * 8] = o;
    } else {
        const int wave = tid >> 6, lane = tid & 63;
        const int u = (b - PREP_HIST_NB - PREP_CVT_NB) * 4 + wave;  // 0..215
        if (u < 64) {
            packB_unit(W1, W1p, u >> 2, u & 3, 4, HIDDEN, lane);
        } else if (u < 192) {
            const int v = u - 64;
            packB_unit(W2, W2p, v >> 3, v & 7, 8, HIDDEN, lane);
        } else {
            const int v = u - 192;
            packB_unit(W3, W3p, v >> 3, v & 7, 8, NCLS, lane);
        }
    }
}

// ---------------- CSR scan ----------------
__global__ __launch_bounds__(SCAN_B) void k_scan_local(const int* __restrict__ counts,
                                                       int* __restrict__ rowp,
                                                       int* __restrict__ partials) {
    __shared__ int s[SCAN_B];
    const int tid = threadIdx.x;
    const int i = blockIdx.x * SCAN_B + tid;
    int v = (i < N_NODES) ? counts[i] : 0;
    s[tid] = v;
    __syncthreads();
    for (int off = 1; off < SCAN_B; off <<= 1) {
        int t = (tid >= off) ? s[tid - off] : 0;
        __syncthreads();
        s[tid] += t;
        __syncthreads();
    }
    if (i < N_NODES) rowp[i] = s[tid] - v;
    if (tid == SCAN_B - 1) partials[blockIdx.x] = s[SCAN_B - 1];
}

__global__ __launch_bounds__(SCAN_B) void k_scan_add(int* __restrict__ rowp,
                                                     int* __restrict__ cursor,
                                                     const int* __restrict__ partials,
                                                     const int* __restrict__ counts,
                                                     float* __restrict__ dinv) {
    __shared__ int s[SCAN_B];
    const int tid = threadIdx.x;
    const int b = blockIdx.x;
    int v = (tid < b) ? partials[tid] : 0;
    s[tid] = v;
    __syncthreads();
    for (int off = SCAN_B / 2; off > 0; off >>= 1) {
        if (tid < off) s[tid] += s[tid + off];
        __syncthreads();
    }
    const int offset = s[0];
    const int i = b * SCAN_B + tid;
    if (i < N_NODES) {
        int r = rowp[i] + offset;
        rowp[i] = r;
        cursor[i] = r;
        dinv[i] = rsqrtf(1.0f + (float)counts[i]);
    }
    if (b == 0 && tid == 0) rowp[N_NODES] = N_EDGES;
}

// scatter: packed (src, wnorm) per edge -> single 8B random store
__global__ void k_scatter(const int* __restrict__ src, const int* __restrict__ dst,
                          int* __restrict__ cursor, const float* __restrict__ dinv,
                          int2* __restrict__ edat) {
    int e = blockIdx.x * blockDim.x + threadIdx.x;
    if (e < N_EDGES) {
        int d = dst[e], s = src[e];
        int p = atomicAdd(&cursor[d], 1);
        int2 v; v.x = s; v.y = __float_as_int(dinv[s] * dinv[d]);
        edat[p] = v;
    }
}

// ---------------- fused layer: parallel-row gather -> LDS -> MFMA f16 --------
// Block: 16 nodes, 4 per wave via 16-lane subgroups. Edge loop: branch-free
// batches with a SINGLE asm carrying ALL loaded vectors as "+v" operands —
// every load result must be live at one program point, so the compiler must
// issue all loads back-to-back into distinct VGPRs before one waitcnt.
// (R3's sched_barrier and R6's per-value asm both failed: VGPR stayed 48,
// loads stayed serialized. One-asm-all-operands is semantically airtight.)
template <int KIN>
__global__ __launch_bounds__(256, 4) void k_fused(const _Float16* __restrict__ Xin,
                                                  const int* __restrict__ rowp,
                                                  const int2* __restrict__ edat,
                                                  const float* __restrict__ dinv,
                                                  const _Float16* __restrict__ Bp,
                                                  const float* __restrict__ bias,
                                                  _Float16* __restrict__ C,
                                                  float* __restrict__ bnp2) {
    constexpr int nkt = KIN / 32;
    constexpr int LROW = KIN + 8;
    constexpr int RW8 = KIN / 8;                 // f16x8 words per feature row
    constexpr int NL = KIN / 128;                // f16x8 loads per lane per row
    __shared__ __align__(16) _Float16 At[16 * LROW];
    const int wave = threadIdx.x >> 6;
    const int lane = threadIdx.x & 63;
    const int sub  = lane >> 4;                  // node slot within wave
    const int t    = lane & 15;                  // lane within subgroup
    const int sb   = lane & 48;                  // subgroup base lane
    const int node = blockIdx.x * 16 + wave * 4 + sub;

    const int e0 = rowp[node];
    const int deg = rowp[node + 1] - e0;
    // coalesced preload of up to 16 (src, w) pairs into the subgroup's lanes
    int   pidx = 0;
    float pw   = 0.f;
    if (t < deg) {
        const int2 e = edat[e0 + t];
        pidx = e.x;
        pw = __int_as_float(e.y);
    }
    const float dd = dinv[node];
    const f16x2 sw2 = (f16x2)(_Float16)(dd * dd);

    const f16x8* __restrict__ Xr = (const f16x8*)Xin;
    union U8 { f16x8 v; f16x2 h[4]; };

    U8 a[NL];
#pragma unroll
    for (int q = 0; q < NL; q++) {
        U8 r; r.v = Xr[(size_t)node * RW8 + q * 16 + t];
#pragma unroll
        for (int p = 0; p < 4; p++) a[q].h[p] = sw2 * r.h[p];
    }

    auto fmaacc = [&](U8& r, _Float16 w, int q) {
        const f16x2 w2 = (f16x2)w;
#pragma unroll
        for (int p = 0; p < 4; p++) a[q].h[p] = w2 * r.h[p] + a[q].h[p];
    };

    if constexpr (NL == 1) {
        // 16 edges, 16 loads, ALL live at the single asm point (64 VGPRs)
        int bi[16]; _Float16 bw[16];
#pragma unroll
        for (int j = 0; j < 16; j++) {
            const int   v  = __shfl(pidx, sb + j);
            const float wv = __shfl(pw,  sb + j);
            const bool ok = j < deg;
            bi[j] = ok ? v : node;                      // dummy: self row (cache hit)
            bw[j] = ok ? (_Float16)wv : (_Float16)0.f;  // dummy: exact no-op
        }
        U8 r0, r1, r2, r3, r4, r5, r6, r7, r8, r9, r10, r11, r12, r13, r14, r15;
        r0.v  = Xr[(size_t)bi[0]  * RW8 + t];
        r1.v  = Xr[(size_t)bi[1]  * RW8 + t];
        r2.v  = Xr[(size_t)bi[2]  * RW8 + t];
        r3.v  = Xr[(size_t)bi[3]  * RW8 + t];
        r4.v  = Xr[(size_t)bi[4]  * RW8 + t];
        r5.v  = Xr[(size_t)bi[5]  * RW8 + t];
        r6.v  = Xr[(size_t)bi[6]  * RW8 + t];
        r7.v  = Xr[(size_t)bi[7]  * RW8 + t];
        r8.v  = Xr[(size_t)bi[8]  * RW8 + t];
        r9.v  = Xr[(size_t)bi[9]  * RW8 + t];
        r10.v = Xr[(size_t)bi[10] * RW8 + t];
        r11.v = Xr[(size_t)bi[11] * RW8 + t];
        r12.v = Xr[(size_t)bi[12] * RW8 + t];
        r13.v = Xr[(size_t)bi[13] * RW8 + t];
        r14.v = Xr[(size_t)bi[14] * RW8 + t];
        r15.v = Xr[(size_t)bi[15] * RW8 + t];
        asm volatile("" : "+v"(r0.v), "+v"(r1.v), "+v"(r2.v), "+v"(r3.v),
                          "+v"(r4.v), "+v"(r5.v), "+v"(r6.v), "+v"(r7.v),
                          "+v"(r8.v), "+v"(r9.v), "+v"(r10.v), "+v"(r11.v),
                          "+v"(r12.v), "+v"(r13.v), "+v"(r14.v), "+v"(r15.v));
        fmaacc(r0, bw[0], 0);   fmaacc(r1, bw[1], 0);
        fmaacc(r2, bw[2], 0);   fmaacc(r3, bw[3], 0);
        fmaacc(r4, bw[4], 0);   fmaacc(r5, bw[5], 0);
        fmaacc(r6, bw[6], 0);   fmaacc(r7, bw[7], 0);
        fmaacc(r8, bw[8], 0);   fmaacc(r9, bw[9], 0);
        fmaacc(r10, bw[10], 0); fmaacc(r11, bw[11], 0);
        fmaacc(r12, bw[12], 0); fmaacc(r13, bw[13], 0);
        fmaacc(r14, bw[14], 0); fmaacc(r15, bw[15], 0);
    } else {
        // 8 edges x 2 words per batch, all 16 loads live at one asm point
        auto batch8 = [&](int j0) {
            int bi[8]; _Float16 bw[8];
#pragma unroll
            for (int j = 0; j < 8; j++) {
                const int   v  = __shfl(pidx, sb + j0 + j);
                const float wv = __shfl(pw,  sb + j0 + j);
                const bool ok = (j0 + j) < deg;
                bi[j] = ok ? v : node;
                bw[j] = ok ? (_Float16)wv : (_Float16)0.f;
            }
            U8 r0, r1, r2, r3, r4, r5, r6, r7;
            U8 s0, s1, s2, s3, s4, s5, s6, s7;
            r0.v = Xr[(size_t)bi[0] * RW8 + t];
            s0.v = Xr[(size_t)bi[0] * RW8 + 16 + t];
            r1.v = Xr[(size_t)bi[1] * RW8 + t];
            s1.v = Xr[(size_t)bi[1] * RW8 + 16 + t];
            r2.v = Xr[(size_t)bi[2] * RW8 + t];
            s2.v = Xr[(size_t)bi[2] * RW8 + 16 + t];
            r3.v = Xr[(size_t)bi[3] * RW8 + t];
            s3.v = Xr[(size_t)bi[3] * RW8 + 16 + t];
            r4.v = Xr[(size_t)bi[4] * RW8 + t];
            s4.v = Xr[(size_t)bi[4] * RW8 + 16 + t];
            r5.v = Xr[(size_t)bi[5] * RW8 + t];
            s5.v = Xr[(size_t)bi[5] * RW8 + 16 + t];
            r6.v = Xr[(size_t)bi[6] * RW8 + t];
            s6.v = Xr[(size_t)bi[6] * RW8 + 16 + t];
            r7.v = Xr[(size_t)bi[7] * RW8 + t];
            s7.v = Xr[(size_t)bi[7] * RW8 + 16 + t];
            asm volatile("" : "+v"(r0.v), "+v"(r1.v), "+v"(r2.v), "+v"(r3.v),
                              "+v"(r4.v), "+v"(r5.v), "+v"(r6.v), "+v"(r7.v),
                              "+v"(s0.v), "+v"(s1.v), "+v"(s2.v), "+v"(s3.v),
                              "+v"(s4.v), "+v"(s5.v), "+v"(s6.v), "+v"(s7.v));
            fmaacc(r0, bw[0], 0); fmaacc(s0, bw[0], 1);
            fmaacc(r1, bw[1], 0); fmaacc(s1, bw[1], 1);
            fmaacc(r2, bw[2], 0); fmaacc(s2, bw[2], 1);
            fmaacc(r3, bw[3], 0); fmaacc(s3, bw[3], 1);
            fmaacc(r4, bw[4], 0); fmaacc(s4, bw[4], 1);
            fmaacc(r5, bw[5], 0); fmaacc(s5, bw[5], 1);
            fmaacc(r6, bw[6], 0); fmaacc(s6, bw[6], 1);
            fmaacc(r7, bw[7], 0); fmaacc(s7, bw[7], 1);
        };
        batch8(0);
        if (__any(deg > 8)) batch8(8);
    }
    if (__any(deg > 16)) {
        for (int j = 16; j < deg; j++) {
            const int2 ed = edat[e0 + j];
            const f16x2 w2 = (f16x2)(_Float16)__int_as_float(ed.y);
#pragma unroll
            for (int q = 0; q < NL; q++) {
                U8 r; r.v = Xr[(size_t)ed.x * RW8 + q * 16 + t];
#pragma unroll
                for (int p = 0; p < 4; p++) a[q].h[p] = w2 * r.h[p] + a[q].h[p];
            }
        }
    }
#pragma unroll
    for (int q = 0; q < NL; q++)
        *(f16x8*)&At[(wave * 4 + sub) * LROW + q * 128 + t * 8] = a[q].v;
    __syncthreads();

    // ---- phase 2: MFMA f16 ----
    const int rowb = blockIdx.x * 16;
    const int ntile0 = wave * 4;
    const _Float16* aL = &At[(lane & 15) * LROW + (lane >> 4) * 8];
    f32x4 acc[4] = {};
#pragma unroll
    for (int kt = 0; kt < nkt; kt++) {
        f16x8 af = *(const f16x8*)(aL + kt * 32);
#pragma unroll
        for (int nt = 0; nt < 4; nt++) {
            f16x8 bfr = *(const f16x8*)(Bp + (((size_t)(ntile0 + nt) * nkt + kt) * 64 + lane) * 8);
            acc[nt] = __builtin_amdgcn_mfma_f32_16x16x32_f16(af, bfr, acc[nt], 0, 0, 0);
        }
    }
    const int rg = lane >> 4, cc = lane & 15;    // C/D: col=lane&15, row=rg*4+i
    float s[4], q2[4];
#pragma unroll
    for (int nt = 0; nt < 4; nt++) {
        const int col = (ntile0 + nt) * 16 + cc;
        const float b = bias[col];
        f32x4 a2 = acc[nt];
        a2[0] += b; a2[1] += b; a2[2] += b; a2[3] += b;
        const size_t base = (size_t)(rowb + rg * 4) * HIDDEN + col;
#pragma unroll
        for (int i = 0; i < 4; i++) C[base + (size_t)i * HIDDEN] = (_Float16)a2[i];
        s[nt] = a2[0] + a2[1] + a2[2] + a2[3];
        q2[nt] = a2[0]*a2[0] + a2[1]*a2[1] + a2[2]*a2[2] + a2[3]*a2[3];
    }
#pragma unroll
    for (int nt = 0; nt < 4; nt++) {
        s[nt] += __shfl_xor(s[nt], 16); s[nt] += __shfl_xor(s[nt], 32);
        q2[nt] += __shfl_xor(q2[nt], 16); q2[nt] += __shfl_xor(q2[nt], 32);
    }
    if (lane < 16) {
        float* dst = bnp2 + ((blockIdx.x & 31) * 512) + ntile0 * 16 + lane;
#pragma unroll
        for (int nt = 0; nt < 4; nt++) {
            atomicAdd(&dst[nt * 16], s[nt]);
            atomicAdd(&dst[nt * 16 + 256], q2[nt]);
        }
    }
}

// ---------------- BN prep: bnp2[32][512] -> scale/shift ----------------
__global__ __launch_bounds__(256) void k_bnprep(const float* __restrict__ bnp2,
                                                const float* __restrict__ g,
                                                const float* __restrict__ be,
                                                float* __restrict__ scale,
                                                float* __restrict__ shift) {
    const int f = threadIdx.x;
    float s = 0.f, q = 0.f;
#pragma unroll
    for (int b = 0; b < 32; b++) {
        s += bnp2[(size_t)b * 512 + f];
        q += bnp2[(size_t)b * 512 + 256 + f];
    }
    const float inv_n = 1.0f / (float)N_NODES;
    float mean = s * inv_n;
    float var = q * inv_n - mean * mean;
    var = fmaxf(var, 0.f);
    float sc = g[f] * rsqrtf(var + BN_EPS);
    scale[f] = sc;
    shift[f] = be[f] - mean * sc;
}

// ---------------- BN apply (in-place): H = relu(bn(H)) ----------------
__global__ __launch_bounds__(256) void k_bnapply(_Float16* __restrict__ H,
                                                 const float* __restrict__ scale,
                                                 const float* __restrict__ shift) {
    const size_t i = (size_t)blockIdx.x * 256 + threadIdx.x;  // f16x8 index
    const int f0 = (int)(i & 31) * 8;                         // feat offset
    union U8 { f16x8 v; f16x2 h[4]; } r;
    r.v = ((const f16x8*)H)[i];
#pragma unroll
    for (int p = 0; p < 4; p++) {
        f16x2 sc = {(_Float16)scale[f0 + 2 * p], (_Float16)scale[f0 + 2 * p + 1]};
        f16x2 sh = {(_Float16)shift[f0 + 2 * p], (_Float16)shift[f0 + 2 * p + 1]};
        r.h[p] = pkmax0(sc * r.h[p] + sh);
    }
    ((f16x8*)H)[i] = r.v;
}

// ---------------- GEMM3: XW3 = relu(bn(H2)) @ W3, fp16 out, 1 wave MT=3 ------
template <int K_>
__global__ __launch_bounds__(64) void k_gemm3(const _Float16* __restrict__ A,
                                              const _Float16* __restrict__ Bp,
                                              const float* __restrict__ scale,
                                              const float* __restrict__ shift,
                                              _Float16* __restrict__ C) {
    constexpr int nkt = K_ / 32;
    constexpr int MT = 3;
    const int lane = threadIdx.x & 63;
    const int rowb = blockIdx.x * 16;
    const int koff = (lane >> 4) * 8;
    const _Float16* aptr = A + (size_t)(rowb + (lane & 15)) * K_ + koff;
    f32x4 acc[MT] = {};
#pragma unroll
    for (int kt = 0; kt < nkt; kt++) {
        union { f16x8 v; f16x2 h[4]; } au, tu;
        au.v = *(const f16x8*)(aptr + kt * 32);
        const int kb = kt * 32 + koff;
#pragma unroll
        for (int p = 0; p < 4; p++) {
            f16x2 sc2 = {(_Float16)scale[kb + 2 * p], (_Float16)scale[kb + 2 * p + 1]};
            f16x2 sh2 = {(_Float16)shift[kb + 2 * p], (_Float16)shift[kb + 2 * p + 1]};
            tu.h[p] = pkmax0(sc2 * au.h[p] + sh2);
        }
#pragma unroll
        for (int nt = 0; nt < MT; nt++) {
            f16x8 bfr = *(const f16x8*)(Bp + (((size_t)nt * nkt + kt) * 64 + lane) * 8);
            acc[nt] = __builtin_amdgcn_mfma_f32_16x16x32_f16(tu.v, bfr, acc[nt], 0, 0, 0);
        }
    }
    const int rg = lane >> 4, cc = lane & 15;
#pragma unroll
    for (int nt = 0; nt < MT; nt++) {
        const int col = nt * 16 + cc;
        if (col < NCLS) {
            const size_t base = (size_t)(rowb + rg * 4) * NCLS + col;
#pragma unroll
            for (int i = 0; i < 4; i++) C[base + (size_t)i * NCLS] = (_Float16)acc[nt][i];
        }
    }
}

// ---------------- output: gather F=40 (fp16) + bias + log_softmax ----------
__global__ __launch_bounds__(256) void k_out(const _Float16* __restrict__ XW,
                                             const int* __restrict__ rowp,
                                             const int2* __restrict__ edat,
                                             const float* __restrict__ dinv,
                                             const float* __restrict__ bias,
                                             float* __restrict__ out) {
    const int wave = threadIdx.x >> 6;
    const int lane = threadIdx.x & 63;
    const int node = blockIdx.x * 4 + wave;
    const float dd = dinv[node];
    const bool act = lane < NCLS;
    const int e0 = rowp[node];
    const int deg = rowp[node + 1] - e0;
    int pidx = 0; float pw = 0.f;
    if (lane < deg) {
        const int2 e = edat[e0 + lane];
        pidx = e.x; pw = __int_as_float(e.y);
    }
    const _Float16* Xl = XW + lane;
    float acc = 0.f;
    if (act) acc = dd * dd * (float)Xl[(size_t)node * NCLS];
    auto batch8 = [&](int j0) {
        int bi[8]; float bw[8];
#pragma unroll
        for (int j = 0; j < 8; j++) {
            const int   v  = __shfl(pidx, j0 + j);
            const float wv = __shfl(pw,  j0 + j);
            const bool ok = (j0 + j) < deg;
            bi[j] = ok ? v : node;
            bw[j] = ok ? wv : 0.f;
        }
        if (act) {
            _Float16 v0 = Xl[(size_t)bi[0] * NCLS];
            _Float16 v1 = Xl[(size_t)bi[1] * NCLS];
            _Float16 v2 = Xl[(size_t)bi[2] * NCLS];
            _Float16 v3 = Xl[(size_t)bi[3] * NCLS];
            _Float16 v4 = Xl[(size_t)bi[4] * NCLS];
            _Float16 v5 = Xl[(size_t)bi[5] * NCLS];
            _Float16 v6 = Xl[(size_t)bi[6] * NCLS];
            _Float16 v7 = Xl[(size_t)bi[7] * NCLS];
            asm volatile("" : "+v"(v0), "+v"(v1), "+v"(v2), "+v"(v3),
                              "+v"(v4), "+v"(v5), "+v"(v6), "+v"(v7));
            acc += bw[0] * (float)v0 + bw[1] * (float)v1
                 + bw[2] * (float)v2 + bw[3] * (float)v3
                 + bw[4] * (float)v4 + bw[5] * (float)v5
                 + bw[6] * (float)v6 + bw[7] * (float)v7;
        }
    };
    batch8(0);
    if (deg > 8) {
        batch8(8);
        if (deg > 16) {
            batch8(16);
            if (deg > 24) {
                batch8(24);
                if (deg > 32) {
                    for (int j = 32; j < deg; j++) {
                        const int2 ed = edat[e0 + j];
                        if (act) acc += __int_as_float(ed.y) * (float)Xl[(size_t)ed.x * NCLS];
                    }
                }
            }
        }
    }
    if (act) acc += bias[lane];
    float m = act ? acc : -1e30f;
#pragma unroll
    for (int off = 32; off > 0; off >>= 1) m = fmaxf(m, __shfl_xor(m, off));
    float e = act ? expf(acc - m) : 0.f;
#pragma unroll
    for (int off = 32; off > 0; off >>= 1) e += __shfl_xor(e, off);
    const float lse = m + logf(e);
    if (act) out[node * NCLS + lane] = acc - lse;
}

extern "C" void kernel_launch(void* const* d_in, const int* in_sizes, int n_in,
                              void* d_out, int out_size, void* d_ws, size_t ws_size,
                              hipStream_t stream) {
    const float* x   = (const float*)d_in[0];
    const int*   ei  = (const int*)d_in[1];
    const float* W1  = (const float*)d_in[2];
    const float* b1  = (const float*)d_in[3];
    const float* g1  = (const float*)d_in[4];
    const float* be1 = (const float*)d_in[5];
    const float* W2  = (const float*)d_in[6];
    const float* b2  = (const float*)d_in[7];
    const float* g2  = (const float*)d_in[8];
    const float* be2 = (const float*)d_in[9];
    const float* W3  = (const float*)d_in[10];
    const float* b3  = (const float*)d_in[11];
    float* out = (float*)d_out;

    const int* e_src = ei;
    const int* e_dst = ei + N_EDGES;

    // ---- workspace layout ----
    char* w = (char*)d_ws;
    _Float16* Xh  = (_Float16*)w;              w += (size_t)N_NODES * IN_FEAT * 2;  // 12.8 MB
    _Float16* H1h = (_Float16*)w;              w += (size_t)N_NODES * HIDDEN * 2;   // 25.6 MB
    _Float16* H2h = (_Float16*)w;              w += (size_t)N_NODES * HIDDEN * 2;   // 25.6 MB
    _Float16* XW3h = (_Float16*)w;             w += (size_t)N_NODES * NCLS * 2;     // 4 MB
    float* dinv   = (float*)w;                 w += (size_t)N_NODES * 4;
    int2*  edat   = (int2*)w;                  w += (size_t)N_EDGES * 8;            // 2.56 MB
    // --- contiguous zero-init region (single memset) ---
    int*   counts = (int*)w;                   w += (size_t)N_NODES * 4;            // 200000 B
    float* bnp2a  = (float*)w;                 w += (size_t)32 * 512 * 4;           // 64 KB
    float* bnp2b  = (float*)w;                 w += (size_t)32 * 512 * 4;           // 64 KB
    // ---
    int*   rowp   = (int*)w;                   w += (size_t)(N_NODES + 4) * 4;
    int*   cursor = (int*)w;                   w += (size_t)N_NODES * 4;
    int*   partials=(int*)w;                   w += 256 * 4;
    float* scale1 = (float*)w;                 w += 256 * 4;
    float* shift1 = (float*)w;                 w += 256 * 4;
    float* scale2 = (float*)w;                 w += 256 * 4;
    float* shift2 = (float*)w;                 w += 256 * 4;
    _Float16* W1p = (_Float16*)w;              w += (size_t)16 * 4 * 64 * 8 * 2;    // 64 KB
    _Float16* W2p = (_Float16*)w;              w += (size_t)16 * 8 * 64 * 8 * 2;    // 128 KB
    _Float16* W3p = (_Float16*)w;              w += (size_t)3 * 8 * 64 * 8 * 2;     // 24 KB

    const int EB = (N_EDGES + 255) / 256;

    // ---- CSR build + prep (hist fused with cast/pack) ----
    hipMemsetAsync(counts, 0, (size_t)N_NODES * 4 + 2 * (size_t)32 * 512 * 4, stream);
    k_prep<<<PREP_HIST_NB + PREP_CVT_NB + PREP_PACK_NB, 256, 0, stream>>>(
        e_dst, counts, x, Xh, W1, W2, W3, W1p, W2p, W3p);
    k_scan_local<<<SCAN_NB, SCAN_B, 0, stream>>>(counts, rowp, partials);
    k_scan_add<<<SCAN_NB, SCAN_B, 0, stream>>>(rowp, cursor, partials, counts, dinv);
    k_scatter<<<EB, 256, 0, stream>>>(e_src, e_dst, cursor, dinv, edat);

    // ---- layer 1: fused (gather X -> MFMA W1 + b1 -> H1h, stats) ----
    k_fused<IN_FEAT><<<GNB, 256, 0, stream>>>(
        Xh, rowp, edat, dinv, W1p, b1, H1h, bnp2a);
    k_bnprep<<<1, 256, 0, stream>>>(bnp2a, g1, be1, scale1, shift1);
    k_bnapply<<<BNA_NB, 256, 0, stream>>>(H1h, scale1, shift1);

    // ---- layer 2: fused (gather H1' -> MFMA W2 + b2 -> H2h, stats) ----
    k_fused<HIDDEN><<<GNB, 256, 0, stream>>>(
        H1h, rowp, edat, dinv, W2p, b2, H2h, bnp2b);
    k_bnprep<<<1, 256, 0, stream>>>(bnp2b, g2, be2, scale2, shift2);

    // ---- output layer ----
    k_gemm3<HIDDEN><<<GNB, 64, 0, stream>>>(H2h, W3p, scale2, shift2, XW3h);
    k_out<<<N_NODES / 4, 256, 0, stream>>>(XW3h, rowp, edat, dinv, b3, out);
}

// Round 9
// 242.743 us; speedup vs baseline: 1.0120x; 1.0120x over previous
//
#include <hip/hip_runtime.h>

#define N_NODES 50000
#define N_EDGES 320000
#define IN_FEAT 128
#define HIDDEN  256
#define NCLS    40
#define OPAD    64                                  // padded out-cols (2 lines)
#define BN_EPS  1e-5f

#define SCAN_B  256
#define SCAN_NB ((N_NODES + SCAN_B - 1) / SCAN_B)   // 196
#define GNB     (N_NODES / 16)                      // 3125 blocks, 16 nodes each

// prep kernel partition
#define PREP_HIST_NB  (N_EDGES / 256)               // 1250
#define PREP_CVT_NB   (N_NODES * IN_FEAT / 8 / 256) // 3125
#define PREP_PACK_NB  54                            // 216 wave-units / 4

typedef __attribute__((ext_vector_type(8))) _Float16 f16x8;
typedef __attribute__((ext_vector_type(2))) _Float16 f16x2;
typedef __attribute__((ext_vector_type(4))) float f32x4;

__device__ __forceinline__ f16x2 pkmax0(f16x2 a) {
    return __builtin_elementwise_max(a, (f16x2)(_Float16)0.f);
}

__device__ __forceinline__ void packB_unit(const float* __restrict__ W,
                                           _Float16* __restrict__ Bp,
                                           int nt, int kt, int nkt, int M, int lane) {
    const int n = nt * 16 + (lane & 15);
    const int kb = kt * 32 + (lane >> 4) * 8;
    _Float16* dst = Bp + (((size_t)nt * nkt + kt) * 64 + lane) * 8;
#pragma unroll
    for (int j = 0; j < 8; j++)
        dst[j] = (n < M) ? (_Float16)W[(size_t)(kb + j) * M + n] : (_Float16)0.f;
}

// ---------------- merged prep: hist + x cast + W packs ----------------
__global__ __launch_bounds__(256) void k_prep(const int* __restrict__ e_dst,
                                              int* __restrict__ counts,
                                              const float* __restrict__ x,
                                              _Float16* __restrict__ Xh,
                                              const float* __restrict__ W1,
                                              const float* __restrict__ W2,
                                              const float* __restrict__ W3,
                                              _Float16* __restrict__ W1p,
                                              _Float16* __restrict__ W2p,
                                              _Float16* __restrict__ W3p) {
    const int b = blockIdx.x;
    const int tid = threadIdx.x;
    if (b < PREP_HIST_NB) {
        const int e = b * 256 + tid;                  // 1250*256 == N_EDGES
        atomicAdd(&counts[e_dst[e]], 1);
    } else if (b < PREP_HIST_NB + PREP_CVT_NB) {
        const int i = (b - PREP_HIST_NB) * 256 + tid; // exact cover
        float4 a = *(const float4*)(x + (size_t)i * 8);
        float4 c = *(const float4*)(x + (size_t)i * 8 + 4);
        f16x8 o = {(_Float16)a.x, (_Float16)a.y, (_Float16)a.z, (_Float16)a.w,
                   (_Float16)c.x, (_Float16)c.y, (_Float16)c.z, (_Float16)c.w};
        *(f16x8*)&Xh[(size_t)i * 8] = o;
    } else {
        const int wave = tid >> 6, lane = tid & 63;
        const int u = (b - PREP_HIST_NB - PREP_CVT_NB) * 4 + wave;  // 0..215
        if (u < 64) {
            packB_unit(W1, W1p, u >> 2, u & 3, 4, HIDDEN, lane);
        } else if (u < 192) {
            const int v = u - 64;
            packB_unit(W2, W2p, v >> 3, v & 7, 8, HIDDEN, lane);
        } else {
            const int v = u - 192;
            packB_unit(W3, W3p, v >> 3, v & 7, 8, NCLS, lane);
        }
    }
}

// ---------------- CSR scan ----------------
__global__ __launch_bounds__(SCAN_B) void k_scan_local(const int* __restrict__ counts,
                                                       int* __restrict__ rowp,
                                                       int* __restrict__ partials) {
    __shared__ int s[SCAN_B];
    const int tid = threadIdx.x;
    const int i = blockIdx.x * SCAN_B + tid;
    int v = (i < N_NODES) ? counts[i] : 0;
    s[tid] = v;
    __syncthreads();
    for (int off = 1; off < SCAN_B; off <<= 1) {
        int t = (tid >= off) ? s[tid - off] : 0;
        __syncthreads();
        s[tid] += t;
        __syncthreads();
    }
    if (i < N_NODES) rowp[i] = s[tid] - v;
    if (tid == SCAN_B - 1) partials[blockIdx.x] = s[SCAN_B - 1];
}

__global__ __launch_bounds__(SCAN_B) void k_scan_add(int* __restrict__ rowp,
                                                     int* __restrict__ cursor,
                                                     const int* __restrict__ partials,
                                                     const int* __restrict__ counts,
                                                     float* __restrict__ dinv) {
    __shared__ int s[SCAN_B];
    const int tid = threadIdx.x;
    const int b = blockIdx.x;
    int v = (tid < b) ? partials[tid] : 0;
    s[tid] = v;
    __syncthreads();
    for (int off = SCAN_B / 2; off > 0; off >>= 1) {
        if (tid < off) s[tid] += s[tid + off];
        __syncthreads();
    }
    const int offset = s[0];
    const int i = b * SCAN_B + tid;
    if (i < N_NODES) {
        int r = rowp[i] + offset;
        rowp[i] = r;
        cursor[i] = r;
        dinv[i] = rsqrtf(1.0f + (float)counts[i]);
    }
    if (b == 0 && tid == 0) rowp[N_NODES] = N_EDGES;
}

// scatter: packed (src, wnorm) per edge -> single 8B random store
__global__ void k_scatter(const int* __restrict__ src, const int* __restrict__ dst,
                          int* __restrict__ cursor, const float* __restrict__ dinv,
                          int2* __restrict__ edat) {
    int e = blockIdx.x * blockDim.x + threadIdx.x;
    if (e < N_EDGES) {
        int d = dst[e], s = src[e];
        int p = atomicAdd(&cursor[d], 1);
        int2 v; v.x = s; v.y = __float_as_int(dinv[s] * dinv[d]);
        edat[p] = v;
    }
}

// ---------------- fused layer: parallel-row gather -> LDS -> MFMA f16 --------
// Block: 16 nodes, 4 per wave via 16-lane subgroups; branch-free asm-batched
// edge loop (R8). BN+ReLU is applied PER-EDGE inside the gather when BN=true:
// under the measured per-CU outstanding-line cap (~4.4 TB/s logical gather,
// invariant across 6 structures R0-R8), extra VALU in the gather is free
// (R0 46.1 with BN == R1 46.4 without) — this deletes the k_bnapply pass
// (8 us + 51 MB streaming + 1 launch).
template <int KIN, bool BN>
__global__ __launch_bounds__(256, 4) void k_fused(const _Float16* __restrict__ Xin,
                                                  const int* __restrict__ rowp,
                                                  const int2* __restrict__ edat,
                                                  const float* __restrict__ dinv,
                                                  const float* __restrict__ scale,
                                                  const float* __restrict__ shift,
                                                  const _Float16* __restrict__ Bp,
                                                  const float* __restrict__ bias,
                                                  _Float16* __restrict__ C,
                                                  float* __restrict__ bnp2) {
    constexpr int nkt = KIN / 32;
    constexpr int LROW = KIN + 8;
    constexpr int RW8 = KIN / 8;                 // f16x8 words per feature row
    constexpr int NL = KIN / 128;                // f16x8 loads per lane per row
    __shared__ __align__(16) _Float16 At[16 * LROW];
    const int wave = threadIdx.x >> 6;
    const int lane = threadIdx.x & 63;
    const int sub  = lane >> 4;                  // node slot within wave
    const int t    = lane & 15;                  // lane within subgroup
    const int sb   = lane & 48;                  // subgroup base lane
    const int node = blockIdx.x * 16 + wave * 4 + sub;

    const int e0 = rowp[node];
    const int deg = rowp[node + 1] - e0;
    // coalesced preload of up to 16 (src, w) pairs into the subgroup's lanes
    int   pidx = 0;
    float pw   = 0.f;
    if (t < deg) {
        const int2 e = edat[e0 + t];
        pidx = e.x;
        pw = __int_as_float(e.y);
    }
    const float dd = dinv[node];
    const f16x2 sw2 = (f16x2)(_Float16)(dd * dd);

    // per-lane BN constants for the feature slots this lane covers
    f16x2 scq[NL][4], shq[NL][4];
    if constexpr (BN) {
#pragma unroll
        for (int q = 0; q < NL; q++)
#pragma unroll
            for (int p = 0; p < 4; p++) {
                const int f0 = q * 128 + t * 8 + 2 * p;
                scq[q][p] = f16x2{(_Float16)scale[f0], (_Float16)scale[f0 + 1]};
                shq[q][p] = f16x2{(_Float16)shift[f0], (_Float16)shift[f0 + 1]};
            }
    }

    const f16x8* __restrict__ Xr = (const f16x8*)Xin;
    union U8 { f16x8 v; f16x2 h[4]; };

    U8 a[NL];
#pragma unroll
    for (int q = 0; q < NL; q++) {
        U8 r; r.v = Xr[(size_t)node * RW8 + q * 16 + t];
#pragma unroll
        for (int p = 0; p < 4; p++) {
            f16x2 v = r.h[p];
            if constexpr (BN) v = pkmax0(scq[q][p] * v + shq[q][p]);
            a[q].h[p] = sw2 * v;
        }
    }

    auto proc = [&](U8& r, _Float16 w, int q) {
        const f16x2 w2 = (f16x2)w;
#pragma unroll
        for (int p = 0; p < 4; p++) {
            f16x2 v = r.h[p];
            if constexpr (BN) v = pkmax0(scq[q][p] * v + shq[q][p]);
            a[q].h[p] = w2 * v + a[q].h[p];
        }
    };

    if constexpr (NL == 1) {
        // 16 edges, 16 loads, all live at the single asm point
        int bi[16]; _Float16 bw[16];
#pragma unroll
        for (int j = 0; j < 16; j++) {
            const int   v  = __shfl(pidx, sb + j);
            const float wv = __shfl(pw,  sb + j);
            const bool ok = j < deg;
            bi[j] = ok ? v : node;                      // dummy: self row (cache hit)
            bw[j] = ok ? (_Float16)wv : (_Float16)0.f;  // dummy: exact no-op
        }
        U8 r0, r1, r2, r3, r4, r5, r6, r7, r8, r9, r10, r11, r12, r13, r14, r15;
        r0.v  = Xr[(size_t)bi[0]  * RW8 + t];
        r1.v  = Xr[(size_t)bi[1]  * RW8 + t];
        r2.v  = Xr[(size_t)bi[2]  * RW8 + t];
        r3.v  = Xr[(size_t)bi[3]  * RW8 + t];
        r4.v  = Xr[(size_t)bi[4]  * RW8 + t];
        r5.v  = Xr[(size_t)bi[5]  * RW8 + t];
        r6.v  = Xr[(size_t)bi[6]  * RW8 + t];
        r7.v  = Xr[(size_t)bi[7]  * RW8 + t];
        r8.v  = Xr[(size_t)bi[8]  * RW8 + t];
        r9.v  = Xr[(size_t)bi[9]  * RW8 + t];
        r10.v = Xr[(size_t)bi[10] * RW8 + t];
        r11.v = Xr[(size_t)bi[11] * RW8 + t];
        r12.v = Xr[(size_t)bi[12] * RW8 + t];
        r13.v = Xr[(size_t)bi[13] * RW8 + t];
        r14.v = Xr[(size_t)bi[14] * RW8 + t];
        r15.v = Xr[(size_t)bi[15] * RW8 + t];
        asm volatile("" : "+v"(r0.v), "+v"(r1.v), "+v"(r2.v), "+v"(r3.v),
                          "+v"(r4.v), "+v"(r5.v), "+v"(r6.v), "+v"(r7.v),
                          "+v"(r8.v), "+v"(r9.v), "+v"(r10.v), "+v"(r11.v),
                          "+v"(r12.v), "+v"(r13.v), "+v"(r14.v), "+v"(r15.v));
        proc(r0, bw[0], 0);   proc(r1, bw[1], 0);
        proc(r2, bw[2], 0);   proc(r3, bw[3], 0);
        proc(r4, bw[4], 0);   proc(r5, bw[5], 0);
        proc(r6, bw[6], 0);   proc(r7, bw[7], 0);
        proc(r8, bw[8], 0);   proc(r9, bw[9], 0);
        proc(r10, bw[10], 0); proc(r11, bw[11], 0);
        proc(r12, bw[12], 0); proc(r13, bw[13], 0);
        proc(r14, bw[14], 0); proc(r15, bw[15], 0);
    } else {
        // 8 edges x 2 words per batch, all 16 loads live at one asm point
        auto batch8 = [&](int j0) {
            int bi[8]; _Float16 bw[8];
#pragma unroll
            for (int j = 0; j < 8; j++) {
                const int   v  = __shfl(pidx, sb + j0 + j);
                const float wv = __shfl(pw,  sb + j0 + j);
                const bool ok = (j0 + j) < deg;
                bi[j] = ok ? v : node;
                bw[j] = ok ? (_Float16)wv : (_Float16)0.f;
            }
            U8 r0, r1, r2, r3, r4, r5, r6, r7;
            U8 s0, s1, s2, s3, s4, s5, s6, s7;
            r0.v = Xr[(size_t)bi[0] * RW8 + t];
            s0.v = Xr[(size_t)bi[0] * RW8 + 16 + t];
            r1.v = Xr[(size_t)bi[1] * RW8 + t];
            s1.v = Xr[(size_t)bi[1] * RW8 + 16 + t];
            r2.v = Xr[(size_t)bi[2] * RW8 + t];
            s2.v = Xr[(size_t)bi[2] * RW8 + 16 + t];
            r3.v = Xr[(size_t)bi[3] * RW8 + t];
            s3.v = Xr[(size_t)bi[3] * RW8 + 16 + t];
            r4.v = Xr[(size_t)bi[4] * RW8 + t];
            s4.v = Xr[(size_t)bi[4] * RW8 + 16 + t];
            r5.v = Xr[(size_t)bi[5] * RW8 + t];
            s5.v = Xr[(size_t)bi[5] * RW8 + 16 + t];
            r6.v = Xr[(size_t)bi[6] * RW8 + t];
            s6.v = Xr[(size_t)bi[6] * RW8 + 16 + t];
            r7.v = Xr[(size_t)bi[7] * RW8 + t];
            s7.v = Xr[(size_t)bi[7] * RW8 + 16 + t];
            asm volatile("" : "+v"(r0.v), "+v"(r1.v), "+v"(r2.v), "+v"(r3.v),
                              "+v"(r4.v), "+v"(r5.v), "+v"(r6.v), "+v"(r7.v),
                              "+v"(s0.v), "+v"(s1.v), "+v"(s2.v), "+v"(s3.v),
                              "+v"(s4.v), "+v"(s5.v), "+v"(s6.v), "+v"(s7.v));
            proc(r0, bw[0], 0); proc(s0, bw[0], 1);
            proc(r1, bw[1], 0); proc(s1, bw[1], 1);
            proc(r2, bw[2], 0); proc(s2, bw[2], 1);
            proc(r3, bw[3], 0); proc(s3, bw[3], 1);
            proc(r4, bw[4], 0); proc(s4, bw[4], 1);
            proc(r5, bw[5], 0); proc(s5, bw[5], 1);
            proc(r6, bw[6], 0); proc(s6, bw[6], 1);
            proc(r7, bw[7], 0); proc(s7, bw[7], 1);
        };
        batch8(0);
        if (__any(deg > 8)) batch8(8);
    }
    if (__any(deg > 16)) {
        for (int j = 16; j < deg; j++) {
            const int2 ed = edat[e0 + j];
            const _Float16 wj = (_Float16)__int_as_float(ed.y);
#pragma unroll
            for (int q = 0; q < NL; q++) {
                U8 r; r.v = Xr[(size_t)ed.x * RW8 + q * 16 + t];
                proc(r, wj, q);
            }
        }
    }
#pragma unroll
    for (int q = 0; q < NL; q++)
        *(f16x8*)&At[(wave * 4 + sub) * LROW + q * 128 + t * 8] = a[q].v;
    __syncthreads();

    // ---- phase 2: MFMA f16 ----
    const int rowb = blockIdx.x * 16;
    const int ntile0 = wave * 4;
    const _Float16* aL = &At[(lane & 15) * LROW + (lane >> 4) * 8];
    f32x4 acc[4] = {};
#pragma unroll
    for (int kt = 0; kt < nkt; kt++) {
        f16x8 af = *(const f16x8*)(aL + kt * 32);
#pragma unroll
        for (int nt = 0; nt < 4; nt++) {
            f16x8 bfr = *(const f16x8*)(Bp + (((size_t)(ntile0 + nt) * nkt + kt) * 64 + lane) * 8);
            acc[nt] = __builtin_amdgcn_mfma_f32_16x16x32_f16(af, bfr, acc[nt], 0, 0, 0);
        }
    }
    const int rg = lane >> 4, cc = lane & 15;    // C/D: col=lane&15, row=rg*4+i
    float s[4], q2[4];
#pragma unroll
    for (int nt = 0; nt < 4; nt++) {
        const int col = (ntile0 + nt) * 16 + cc;
        const float b = bias[col];
        f32x4 a2 = acc[nt];
        a2[0] += b; a2[1] += b; a2[2] += b; a2[3] += b;
        const size_t base = (size_t)(rowb + rg * 4) * HIDDEN + col;
#pragma unroll
        for (int i = 0; i < 4; i++) C[base + (size_t)i * HIDDEN] = (_Float16)a2[i];
        s[nt] = a2[0] + a2[1] + a2[2] + a2[3];
        q2[nt] = a2[0]*a2[0] + a2[1]*a2[1] + a2[2]*a2[2] + a2[3]*a2[3];
    }
#pragma unroll
    for (int nt = 0; nt < 4; nt++) {
        s[nt] += __shfl_xor(s[nt], 16); s[nt] += __shfl_xor(s[nt], 32);
        q2[nt] += __shfl_xor(q2[nt], 16); q2[nt] += __shfl_xor(q2[nt], 32);
    }
    if (lane < 16) {
        float* dst = bnp2 + ((blockIdx.x & 31) * 512) + ntile0 * 16 + lane;
#pragma unroll
        for (int nt = 0; nt < 4; nt++) {
            atomicAdd(&dst[nt * 16], s[nt]);
            atomicAdd(&dst[nt * 16 + 256], q2[nt]);
        }
    }
}

// ---------------- BN prep: bnp2[32][512] -> scale/shift ----------------
__global__ __launch_bounds__(256) void k_bnprep(const float* __restrict__ bnp2,
                                                const float* __restrict__ g,
                                                const float* __restrict__ be,
                                                float* __restrict__ scale,
                                                float* __restrict__ shift) {
    const int f = threadIdx.x;
    float s = 0.f, q = 0.f;
#pragma unroll
    for (int b = 0; b < 32; b++) {
        s += bnp2[(size_t)b * 512 + f];
        q += bnp2[(size_t)b * 512 + 256 + f];
    }
    const float inv_n = 1.0f / (float)N_NODES;
    float mean = s * inv_n;
    float var = q * inv_n - mean * mean;
    var = fmaxf(var, 0.f);
    float sc = g[f] * rsqrtf(var + BN_EPS);
    scale[f] = sc;
    shift[f] = be[f] - mean * sc;
}

// ---------------- GEMM3: XW3 = relu(bn(H2)) @ W3, fp16 out (stride OPAD) ----
template <int K_>
__global__ __launch_bounds__(64) void k_gemm3(const _Float16* __restrict__ A,
                                              const _Float16* __restrict__ Bp,
                                              const float* __restrict__ scale,
                                              const float* __restrict__ shift,
                                              _Float16* __restrict__ C) {
    constexpr int nkt = K_ / 32;
    constexpr int MT = 3;
    const int lane = threadIdx.x & 63;
    const int rowb = blockIdx.x * 16;
    const int koff = (lane >> 4) * 8;
    const _Float16* aptr = A + (size_t)(rowb + (lane & 15)) * K_ + koff;
    f32x4 acc[MT] = {};
#pragma unroll
    for (int kt = 0; kt < nkt; kt++) {
        union { f16x8 v; f16x2 h[4]; } au, tu;
        au.v = *(const f16x8*)(aptr + kt * 32);
        const int kb = kt * 32 + koff;
#pragma unroll
        for (int p = 0; p < 4; p++) {
            f16x2 sc2 = {(_Float16)scale[kb + 2 * p], (_Float16)scale[kb + 2 * p + 1]};
            f16x2 sh2 = {(_Float16)shift[kb + 2 * p], (_Float16)shift[kb + 2 * p + 1]};
            tu.h[p] = pkmax0(sc2 * au.h[p] + sh2);
        }
#pragma unroll
        for (int nt = 0; nt < MT; nt++) {
            f16x8 bfr = *(const f16x8*)(Bp + (((size_t)nt * nkt + kt) * 64 + lane) * 8);
            acc[nt] = __builtin_amdgcn_mfma_f32_16x16x32_f16(tu.v, bfr, acc[nt], 0, 0, 0);
        }
    }
    const int rg = lane >> 4, cc = lane & 15;
#pragma unroll
    for (int nt = 0; nt < MT; nt++) {
        const int col = nt * 16 + cc;
        if (col < NCLS) {
            const size_t base = (size_t)(rowb + rg * 4) * OPAD + col;
#pragma unroll
            for (int i = 0; i < 4; i++) C[base + (size_t)i * OPAD] = (_Float16)acc[nt][i];
        }
    }
}

// ---------------- output: gather F=40 (fp16, stride OPAD) + log_softmax ----
__global__ __launch_bounds__(256) void k_out(const _Float16* __restrict__ XW,
                                             const int* __restrict__ rowp,
                                             const int2* __restrict__ edat,
                                             const float* __restrict__ dinv,
                                             const float* __restrict__ bias,
                                             float* __restrict__ out) {
    const int wave = threadIdx.x >> 6;
    const int lane = threadIdx.x & 63;
    const int node = blockIdx.x * 4 + wave;
    const float dd = dinv[node];
    const bool act = lane < NCLS;
    const int e0 = rowp[node];
    const int deg = rowp[node + 1] - e0;
    int pidx = 0; float pw = 0.f;
    if (lane < deg) {
        const int2 e = edat[e0 + lane];
        pidx = e.x; pw = __int_as_float(e.y);
    }
    const _Float16* Xl = XW + lane;
    float acc = 0.f;
    if (act) acc = dd * dd * (float)Xl[(size_t)node * OPAD];
    auto batch8 = [&](int j0) {
        int bi[8]; float bw[8];
#pragma unroll
        for (int j = 0; j < 8; j++) {
            const int   v  = __shfl(pidx, j0 + j);
            const float wv = __shfl(pw,  j0 + j);
            const bool ok = (j0 + j) < deg;
            bi[j] = ok ? v : node;
            bw[j] = ok ? wv : 0.f;
        }
        if (act) {
            _Float16 v0 = Xl[(size_t)bi[0] * OPAD];
            _Float16 v1 = Xl[(size_t)bi[1] * OPAD];
            _Float16 v2 = Xl[(size_t)bi[2] * OPAD];
            _Float16 v3 = Xl[(size_t)bi[3] * OPAD];
            _Float16 v4 = Xl[(size_t)bi[4] * OPAD];
            _Float16 v5 = Xl[(size_t)bi[5] * OPAD];
            _Float16 v6 = Xl[(size_t)bi[6] * OPAD];
            _Float16 v7 = Xl[(size_t)bi[7] * OPAD];
            asm volatile("" : "+v"(v0), "+v"(v1), "+v"(v2), "+v"(v3),
                              "+v"(v4), "+v"(v5), "+v"(v6), "+v"(v7));
            acc += bw[0] * (float)v0 + bw[1] * (float)v1
                 + bw[2] * (float)v2 + bw[3] * (float)v3
                 + bw[4] * (float)v4 + bw[5] * (float)v5
                 + bw[6] * (float)v6 + bw[7] * (float)v7;
        }
    };
    batch8(0);
    if (deg > 8) {
        batch8(8);
        if (deg > 16) {
            batch8(16);
            if (deg > 24) {
                batch8(24);
                if (deg > 32) {
                    for (int j = 32; j < deg; j++) {
                        const int2 ed = edat[e0 + j];
                        if (act) acc += __int_as_float(ed.y) * (float)Xl[(size_t)ed.x * OPAD];
                    }
                }
            }
        }
    }
    if (act) acc += bias[lane];
    float m = act ? acc : -1e30f;
#pragma unroll
    for (int off = 32; off > 0; off >>= 1) m = fmaxf(m, __shfl_xor(m, off));
    float e = act ? expf(acc - m) : 0.f;
#pragma unroll
    for (int off = 32; off > 0; off >>= 1) e += __shfl_xor(e, off);
    const float lse = m + logf(e);
    if (act) out[node * NCLS + lane] = acc - lse;
}

extern "C" void kernel_launch(void* const* d_in, const int* in_sizes, int n_in,
                              void* d_out, int out_size, void* d_ws, size_t ws_size,
                              hipStream_t stream) {
    const float* x   = (const float*)d_in[0];
    const int*   ei  = (const int*)d_in[1];
    const float* W1  = (const float*)d_in[2];
    const float* b1  = (const float*)d_in[3];
    const float* g1  = (const float*)d_in[4];
    const float* be1 = (const float*)d_in[5];
    const float* W2  = (const float*)d_in[6];
    const float* b2  = (const float*)d_in[7];
    const float* g2  = (const float*)d_in[8];
    const float* be2 = (const float*)d_in[9];
    const float* W3  = (const float*)d_in[10];
    const float* b3  = (const float*)d_in[11];
    float* out = (float*)d_out;

    const int* e_src = ei;
    const int* e_dst = ei + N_EDGES;

    // ---- workspace layout ----
    char* w = (char*)d_ws;
    _Float16* Xh  = (_Float16*)w;              w += (size_t)N_NODES * IN_FEAT * 2;  // 12.8 MB
    _Float16* H1h = (_Float16*)w;              w += (size_t)N_NODES * HIDDEN * 2;   // 25.6 MB
    _Float16* H2h = (_Float16*)w;              w += (size_t)N_NODES * HIDDEN * 2;   // 25.6 MB
    _Float16* XW3h = (_Float16*)w;             w += (size_t)N_NODES * OPAD * 2;     // 6.4 MB
    float* dinv   = (float*)w;                 w += (size_t)N_NODES * 4;
    int2*  edat   = (int2*)w;                  w += (size_t)N_EDGES * 8;            // 2.56 MB
    // --- contiguous zero-init region (single memset) ---
    int*   counts = (int*)w;                   w += (size_t)N_NODES * 4;            // 200000 B
    float* bnp2a  = (float*)w;                 w += (size_t)32 * 512 * 4;           // 64 KB
    float* bnp2b  = (float*)w;                 w += (size_t)32 * 512 * 4;           // 64 KB
    // ---
    int*   rowp   = (int*)w;                   w += (size_t)(N_NODES + 4) * 4;
    int*   cursor = (int*)w;                   w += (size_t)N_NODES * 4;
    int*   partials=(int*)w;                   w += 256 * 4;
    float* scale1 = (float*)w;                 w += 256 * 4;
    float* shift1 = (float*)w;                 w += 256 * 4;
    float* scale2 = (float*)w;                 w += 256 * 4;
    float* shift2 = (float*)w;                 w += 256 * 4;
    _Float16* W1p = (_Float16*)w;              w += (size_t)16 * 4 * 64 * 8 * 2;    // 64 KB
    _Float16* W2p = (_Float16*)w;              w += (size_t)16 * 8 * 64 * 8 * 2;    // 128 KB
    _Float16* W3p = (_Float16*)w;              w += (size_t)3 * 8 * 64 * 8 * 2;     // 24 KB

    const int EB = (N_EDGES + 255) / 256;

    // ---- CSR build + prep (hist fused with cast/pack) ----
    hipMemsetAsync(counts, 0, (size_t)N_NODES * 4 + 2 * (size_t)32 * 512 * 4, stream);
    k_prep<<<PREP_HIST_NB + PREP_CVT_NB + PREP_PACK_NB, 256, 0, stream>>>(
        e_dst, counts, x, Xh, W1, W2, W3, W1p, W2p, W3p);
    k_scan_local<<<SCAN_NB, SCAN_B, 0, stream>>>(counts, rowp, partials);
    k_scan_add<<<SCAN_NB, SCAN_B, 0, stream>>>(rowp, cursor, partials, counts, dinv);
    k_scatter<<<EB, 256, 0, stream>>>(e_src, e_dst, cursor, dinv, edat);

    // ---- layer 1: fused (gather X -> MFMA W1 + b1 -> H1h, stats) ----
    k_fused<IN_FEAT, false><<<GNB, 256, 0, stream>>>(
        Xh, rowp, edat, dinv, nullptr, nullptr, W1p, b1, H1h, bnp2a);
    k_bnprep<<<1, 256, 0, stream>>>(bnp2a, g1, be1, scale1, shift1);

    // ---- layer 2: fused (gather relu(bn(H1)) per-edge -> MFMA W2 -> H2h) ----
    k_fused<HIDDEN, true><<<GNB, 256, 0, stream>>>(
        H1h, rowp, edat, dinv, scale1, shift1, W2p, b2, H2h, bnp2b);
    k_bnprep<<<1, 256, 0, stream>>>(bnp2b, g2, be2, scale2, shift2);

    // ---- output layer ----
    k_gemm3<HIDDEN><<<GNB, 64, 0, stream>>>(H2h, W3p, scale2, shift2, XW3h);
    k_out<<<N_NODES / 4, 256, 0, stream>>>(XW3h, rowp, edat, dinv, b3, out);
}

// Round 10
// 242.452 us; speedup vs baseline: 1.0132x; 1.0012x over previous
//
#include <hip/hip_runtime.h>

#define N_NODES 50000
#define N_EDGES 320000
#define IN_FEAT 128
#define HIDDEN  256
#define NCLS    40
#define OPAD    64                                  // padded out-cols (2 lines)
#define BN_EPS  1e-5f

#define SCAN_B  256
#define SCAN_NB ((N_NODES + SCAN_B - 1) / SCAN_B)   // 196
#define GNB     (N_NODES / 16)                      // 3125 blocks, 16 nodes each

// prep kernel partition
#define PREP_HIST_NB  (N_EDGES / 256)               // 1250
#define PREP_CVT_NB   (N_NODES * IN_FEAT / 8 / 256) // 3125
#define PREP_PACK_NB  54                            // 216 wave-units / 4

typedef __attribute__((ext_vector_type(8))) _Float16 f16x8;
typedef __attribute__((ext_vector_type(2))) _Float16 f16x2;
typedef __attribute__((ext_vector_type(4))) float f32x4;

__device__ __forceinline__ f16x2 pkmax0(f16x2 a) {
    return __builtin_elementwise_max(a, (f16x2)(_Float16)0.f);
}

__device__ __forceinline__ void packB_unit(const float* __restrict__ W,
                                           _Float16* __restrict__ Bp,
                                           int nt, int kt, int nkt, int M, int lane) {
    const int n = nt * 16 + (lane & 15);
    const int kb = kt * 32 + (lane >> 4) * 8;
    _Float16* dst = Bp + (((size_t)nt * nkt + kt) * 64 + lane) * 8;
#pragma unroll
    for (int j = 0; j < 8; j++)
        dst[j] = (n < M) ? (_Float16)W[(size_t)(kb + j) * M + n] : (_Float16)0.f;
}

// ---------------- merged prep: hist + x cast + W packs ----------------
__global__ __launch_bounds__(256) void k_prep(const int* __restrict__ e_dst,
                                              int* __restrict__ counts,
                                              const float* __restrict__ x,
                                              _Float16* __restrict__ Xh,
                                              const float* __restrict__ W1,
                                              const float* __restrict__ W2,
                                              const float* __restrict__ W3,
                                              _Float16* __restrict__ W1p,
                                              _Float16* __restrict__ W2p,
                                              _Float16* __restrict__ W3p) {
    const int b = blockIdx.x;
    const int tid = threadIdx.x;
    if (b < PREP_HIST_NB) {
        const int e = b * 256 + tid;                  // 1250*256 == N_EDGES
        atomicAdd(&counts[e_dst[e]], 1);
    } else if (b < PREP_HIST_NB + PREP_CVT_NB) {
        const int i = (b - PREP_HIST_NB) * 256 + tid; // exact cover
        float4 a = *(const float4*)(x + (size_t)i * 8);
        float4 c = *(const float4*)(x + (size_t)i * 8 + 4);
        f16x8 o = {(_Float16)a.x, (_Float16)a.y, (_Float16)a.z, (_Float16)a.w,
                   (_Float16)c.x, (_Float16)c.y, (_Float16)c.z, (_Float16)c.w};
        *(f16x8*)&Xh[(size_t)i * 8] = o;
    } else {
        const int wave = tid >> 6, lane = tid & 63;
        const int u = (b - PREP_HIST_NB - PREP_CVT_NB) * 4 + wave;  // 0..215
        if (u < 64) {
            packB_unit(W1, W1p, u >> 2, u & 3, 4, HIDDEN, lane);
        } else if (u < 192) {
            const int v = u - 64;
            packB_unit(W2, W2p, v >> 3, v & 7, 8, HIDDEN, lane);
        } else {
            const int v = u - 192;
            packB_unit(W3, W3p, v >> 3, v & 7, 8, NCLS, lane);
        }
    }
}

// ---------------- CSR scan ----------------
__global__ __launch_bounds__(SCAN_B) void k_scan_local(const int* __restrict__ counts,
                                                       int* __restrict__ rowp,
                                                       int* __restrict__ partials) {
    __shared__ int s[SCAN_B];
    const int tid = threadIdx.x;
    const int i = blockIdx.x * SCAN_B + tid;
    int v = (i < N_NODES) ? counts[i] : 0;
    s[tid] = v;
    __syncthreads();
    for (int off = 1; off < SCAN_B; off <<= 1) {
        int t = (tid >= off) ? s[tid - off] : 0;
        __syncthreads();
        s[tid] += t;
        __syncthreads();
    }
    if (i < N_NODES) rowp[i] = s[tid] - v;
    if (tid == SCAN_B - 1) partials[blockIdx.x] = s[SCAN_B - 1];
}

__global__ __launch_bounds__(SCAN_B) void k_scan_add(int* __restrict__ rowp,
                                                     int* __restrict__ cursor,
                                                     const int* __restrict__ partials,
                                                     const int* __restrict__ counts,
                                                     float* __restrict__ dinv) {
    __shared__ int s[SCAN_B];
    const int tid = threadIdx.x;
    const int b = blockIdx.x;
    int v = (tid < b) ? partials[tid] : 0;
    s[tid] = v;
    __syncthreads();
    for (int off = SCAN_B / 2; off > 0; off >>= 1) {
        if (tid < off) s[tid] += s[tid + off];
        __syncthreads();
    }
    const int offset = s[0];
    const int i = b * SCAN_B + tid;
    if (i < N_NODES) {
        int r = rowp[i] + offset;
        rowp[i] = r;
        cursor[i] = r;
        dinv[i] = rsqrtf(1.0f + (float)counts[i]);
    }
    if (b == 0 && tid == 0) rowp[N_NODES] = N_EDGES;
}

// scatter: packed (src, wnorm) per edge -> single 8B random store
__global__ void k_scatter(const int* __restrict__ src, const int* __restrict__ dst,
                          int* __restrict__ cursor, const float* __restrict__ dinv,
                          int2* __restrict__ edat) {
    int e = blockIdx.x * blockDim.x + threadIdx.x;
    if (e < N_EDGES) {
        int d = dst[e], s = src[e];
        int p = atomicAdd(&cursor[d], 1);
        int2 v; v.x = s; v.y = __float_as_int(dinv[s] * dinv[d]);
        edat[p] = v;
    }
}

// ---------------- fused layer: parallel-row gather -> LDS -> MFMA f16 --------
// Block: 16 nodes, 4 per wave via 16-lane subgroups.
// KIN=128 (no BN): asm-batched 16 loads live at once — the drain-then-short-
//   tail schedule wins when the tail is 1 FMA/load (R8: 43.8 vs 46.7).
// KIN=256 (BN folded): plain predicated batch8 — the BN tail is 3 dependent
//   VALU/f16x2, and R9 showed the mega-asm's vmcnt(0) drain + long tail
//   serializes memory and compute (51.5 us vs R1's 46.1 for this shape).
//   Let the compiler interleave vmcnt(N) waits with per-edge BN+FMA chains.
template <int KIN, bool BN>
__global__ __launch_bounds__(256, 4) void k_fused(const _Float16* __restrict__ Xin,
                                                  const int* __restrict__ rowp,
                                                  const int2* __restrict__ edat,
                                                  const float* __restrict__ dinv,
                                                  const float* __restrict__ scale,
                                                  const float* __restrict__ shift,
                                                  const _Float16* __restrict__ Bp,
                                                  const float* __restrict__ bias,
                                                  _Float16* __restrict__ C,
                                                  float* __restrict__ bnp2) {
    constexpr int nkt = KIN / 32;
    constexpr int LROW = KIN + 8;
    constexpr int RW8 = KIN / 8;                 // f16x8 words per feature row
    constexpr int NL = KIN / 128;                // f16x8 loads per lane per row
    __shared__ __align__(16) _Float16 At[16 * LROW];
    const int wave = threadIdx.x >> 6;
    const int lane = threadIdx.x & 63;
    const int sub  = lane >> 4;                  // node slot within wave
    const int t    = lane & 15;                  // lane within subgroup
    const int sb   = lane & 48;                  // subgroup base lane
    const int node = blockIdx.x * 16 + wave * 4 + sub;

    const int e0 = rowp[node];
    const int deg = rowp[node + 1] - e0;
    // coalesced preload of up to 16 (src, w) pairs into the subgroup's lanes
    int   pidx = 0;
    float pw   = 0.f;
    if (t < deg) {
        const int2 e = edat[e0 + t];
        pidx = e.x;
        pw = __int_as_float(e.y);
    }
    const float dd = dinv[node];
    const f16x2 sw2 = (f16x2)(_Float16)(dd * dd);

    // per-lane BN constants for the feature slots this lane covers
    f16x2 scq[NL][4], shq[NL][4];
    if constexpr (BN) {
#pragma unroll
        for (int q = 0; q < NL; q++)
#pragma unroll
            for (int p = 0; p < 4; p++) {
                const int f0 = q * 128 + t * 8 + 2 * p;
                scq[q][p] = f16x2{(_Float16)scale[f0], (_Float16)scale[f0 + 1]};
                shq[q][p] = f16x2{(_Float16)shift[f0], (_Float16)shift[f0 + 1]};
            }
    }

    const f16x8* __restrict__ Xr = (const f16x8*)Xin;
    union U8 { f16x8 v; f16x2 h[4]; };

    U8 a[NL];
#pragma unroll
    for (int q = 0; q < NL; q++) {
        U8 r; r.v = Xr[(size_t)node * RW8 + q * 16 + t];
#pragma unroll
        for (int p = 0; p < 4; p++) {
            f16x2 v = r.h[p];
            if constexpr (BN) v = pkmax0(scq[q][p] * v + shq[q][p]);
            a[q].h[p] = sw2 * v;
        }
    }

    auto proc = [&](U8& r, _Float16 w, int q) {
        const f16x2 w2 = (f16x2)w;
#pragma unroll
        for (int p = 0; p < 4; p++) {
            f16x2 v = r.h[p];
            if constexpr (BN) v = pkmax0(scq[q][p] * v + shq[q][p]);
            a[q].h[p] = w2 * v + a[q].h[p];
        }
    };

    if constexpr (NL == 1) {
        // 16 edges, 16 loads, all live at the single asm point (short tail)
        int bi[16]; _Float16 bw[16];
#pragma unroll
        for (int j = 0; j < 16; j++) {
            const int   v  = __shfl(pidx, sb + j);
            const float wv = __shfl(pw,  sb + j);
            const bool ok = j < deg;
            bi[j] = ok ? v : node;                      // dummy: self row (cache hit)
            bw[j] = ok ? (_Float16)wv : (_Float16)0.f;  // dummy: exact no-op
        }
        U8 r0, r1, r2, r3, r4, r5, r6, r7, r8, r9, r10, r11, r12, r13, r14, r15;
        r0.v  = Xr[(size_t)bi[0]  * RW8 + t];
        r1.v  = Xr[(size_t)bi[1]  * RW8 + t];
        r2.v  = Xr[(size_t)bi[2]  * RW8 + t];
        r3.v  = Xr[(size_t)bi[3]  * RW8 + t];
        r4.v  = Xr[(size_t)bi[4]  * RW8 + t];
        r5.v  = Xr[(size_t)bi[5]  * RW8 + t];
        r6.v  = Xr[(size_t)bi[6]  * RW8 + t];
        r7.v  = Xr[(size_t)bi[7]  * RW8 + t];
        r8.v  = Xr[(size_t)bi[8]  * RW8 + t];
        r9.v  = Xr[(size_t)bi[9]  * RW8 + t];
        r10.v = Xr[(size_t)bi[10] * RW8 + t];
        r11.v = Xr[(size_t)bi[11] * RW8 + t];
        r12.v = Xr[(size_t)bi[12] * RW8 + t];
        r13.v = Xr[(size_t)bi[13] * RW8 + t];
        r14.v = Xr[(size_t)bi[14] * RW8 + t];
        r15.v = Xr[(size_t)bi[15] * RW8 + t];
        asm volatile("" : "+v"(r0.v), "+v"(r1.v), "+v"(r2.v), "+v"(r3.v),
                          "+v"(r4.v), "+v"(r5.v), "+v"(r6.v), "+v"(r7.v),
                          "+v"(r8.v), "+v"(r9.v), "+v"(r10.v), "+v"(r11.v),
                          "+v"(r12.v), "+v"(r13.v), "+v"(r14.v), "+v"(r15.v));
        proc(r0, bw[0], 0);   proc(r1, bw[1], 0);
        proc(r2, bw[2], 0);   proc(r3, bw[3], 0);
        proc(r4, bw[4], 0);   proc(r5, bw[5], 0);
        proc(r6, bw[6], 0);   proc(r7, bw[7], 0);
        proc(r8, bw[8], 0);   proc(r9, bw[9], 0);
        proc(r10, bw[10], 0); proc(r11, bw[11], 0);
        proc(r12, bw[12], 0); proc(r13, bw[13], 0);
        proc(r14, bw[14], 0); proc(r15, bw[15], 0);
    } else {
        // plain predicated batch8 — compiler interleaves waits with BN+FMA
        auto batch8 = [&](int j0) {
            int bi[8]; _Float16 bw[8];
#pragma unroll
            for (int j = 0; j < 8; j++) {
                const int   v  = __shfl(pidx, sb + j0 + j);
                const float wv = __shfl(pw,  sb + j0 + j);
                const bool ok = (j0 + j) < deg;
                bi[j] = ok ? v : node;
                bw[j] = ok ? (_Float16)wv : (_Float16)0.f;
            }
            U8 r[8][NL];
#pragma unroll
            for (int j = 0; j < 8; j++)
#pragma unroll
                for (int q = 0; q < NL; q++)
                    r[j][q].v = Xr[(size_t)bi[j] * RW8 + q * 16 + t];
#pragma unroll
            for (int j = 0; j < 8; j++)
#pragma unroll
                for (int q = 0; q < NL; q++)
                    proc(r[j][q], bw[j], q);
        };
        batch8(0);
        if (__any(deg > 8)) batch8(8);
    }
    if (__any(deg > 16)) {
        for (int j = 16; j < deg; j++) {
            const int2 ed = edat[e0 + j];
            const _Float16 wj = (_Float16)__int_as_float(ed.y);
#pragma unroll
            for (int q = 0; q < NL; q++) {
                U8 r; r.v = Xr[(size_t)ed.x * RW8 + q * 16 + t];
                proc(r, wj, q);
            }
        }
    }
#pragma unroll
    for (int q = 0; q < NL; q++)
        *(f16x8*)&At[(wave * 4 + sub) * LROW + q * 128 + t * 8] = a[q].v;
    __syncthreads();

    // ---- phase 2: MFMA f16 ----
    const int rowb = blockIdx.x * 16;
    const int ntile0 = wave * 4;
    const _Float16* aL = &At[(lane & 15) * LROW + (lane >> 4) * 8];
    f32x4 acc[4] = {};
#pragma unroll
    for (int kt = 0; kt < nkt; kt++) {
        f16x8 af = *(const f16x8*)(aL + kt * 32);
#pragma unroll
        for (int nt = 0; nt < 4; nt++) {
            f16x8 bfr = *(const f16x8*)(Bp + (((size_t)(ntile0 + nt) * nkt + kt) * 64 + lane) * 8);
            acc[nt] = __builtin_amdgcn_mfma_f32_16x16x32_f16(af, bfr, acc[nt], 0, 0, 0);
        }
    }
    const int rg = lane >> 4, cc = lane & 15;    // C/D: col=lane&15, row=rg*4+i
    float s[4], q2[4];
#pragma unroll
    for (int nt = 0; nt < 4; nt++) {
        const int col = (ntile0 + nt) * 16 + cc;
        const float b = bias[col];
        f32x4 a2 = acc[nt];
        a2[0] += b; a2[1] += b; a2[2] += b; a2[3] += b;
        const size_t base = (size_t)(rowb + rg * 4) * HIDDEN + col;
#pragma unroll
        for (int i = 0; i < 4; i++) C[base + (size_t)i * HIDDEN] = (_Float16)a2[i];
        s[nt] = a2[0] + a2[1] + a2[2] + a2[3];
        q2[nt] = a2[0]*a2[0] + a2[1]*a2[1] + a2[2]*a2[2] + a2[3]*a2[3];
    }
#pragma unroll
    for (int nt = 0; nt < 4; nt++) {
        s[nt] += __shfl_xor(s[nt], 16); s[nt] += __shfl_xor(s[nt], 32);
        q2[nt] += __shfl_xor(q2[nt], 16); q2[nt] += __shfl_xor(q2[nt], 32);
    }
    if (lane < 16) {
        float* dst = bnp2 + ((blockIdx.x & 31) * 512) + ntile0 * 16 + lane;
#pragma unroll
        for (int nt = 0; nt < 4; nt++) {
            atomicAdd(&dst[nt * 16], s[nt]);
            atomicAdd(&dst[nt * 16 + 256], q2[nt]);
        }
    }
}

// ---------------- BN prep: bnp2[32][512] -> scale/shift ----------------
__global__ __launch_bounds__(256) void k_bnprep(const float* __restrict__ bnp2,
                                                const float* __restrict__ g,
                                                const float* __restrict__ be,
                                                float* __restrict__ scale,
                                                float* __restrict__ shift) {
    const int f = threadIdx.x;
    float s = 0.f, q = 0.f;
#pragma unroll
    for (int b = 0; b < 32; b++) {
        s += bnp2[(size_t)b * 512 + f];
        q += bnp2[(size_t)b * 512 + 256 + f];
    }
    const float inv_n = 1.0f / (float)N_NODES;
    float mean = s * inv_n;
    float var = q * inv_n - mean * mean;
    var = fmaxf(var, 0.f);
    float sc = g[f] * rsqrtf(var + BN_EPS);
    scale[f] = sc;
    shift[f] = be[f] - mean * sc;
}

// ---------------- GEMM3: XW3 = relu(bn(H2)) @ W3, fp16 out (stride OPAD) ----
template <int K_>
__global__ __launch_bounds__(64) void k_gemm3(const _Float16* __restrict__ A,
                                              const _Float16* __restrict__ Bp,
                                              const float* __restrict__ scale,
                                              const float* __restrict__ shift,
                                              _Float16* __restrict__ C) {
    constexpr int nkt = K_ / 32;
    constexpr int MT = 3;
    const int lane = threadIdx.x & 63;
    const int rowb = blockIdx.x * 16;
    const int koff = (lane >> 4) * 8;
    const _Float16* aptr = A + (size_t)(rowb + (lane & 15)) * K_ + koff;
    f32x4 acc[MT] = {};
#pragma unroll
    for (int kt = 0; kt < nkt; kt++) {
        union { f16x8 v; f16x2 h[4]; } au, tu;
        au.v = *(const f16x8*)(aptr + kt * 32);
        const int kb = kt * 32 + koff;
#pragma unroll
        for (int p = 0; p < 4; p++) {
            f16x2 sc2 = {(_Float16)scale[kb + 2 * p], (_Float16)scale[kb + 2 * p + 1]};
            f16x2 sh2 = {(_Float16)shift[kb + 2 * p], (_Float16)shift[kb + 2 * p + 1]};
            tu.h[p] = pkmax0(sc2 * au.h[p] + sh2);
        }
#pragma unroll
        for (int nt = 0; nt < MT; nt++) {
            f16x8 bfr = *(const f16x8*)(Bp + (((size_t)nt * nkt + kt) * 64 + lane) * 8);
            acc[nt] = __builtin_amdgcn_mfma_f32_16x16x32_f16(tu.v, bfr, acc[nt], 0, 0, 0);
        }
    }
    const int rg = lane >> 4, cc = lane & 15;
#pragma unroll
    for (int nt = 0; nt < MT; nt++) {
        const int col = nt * 16 + cc;
        if (col < NCLS) {
            const size_t base = (size_t)(rowb + rg * 4) * OPAD + col;
#pragma unroll
            for (int i = 0; i < 4; i++) C[base + (size_t)i * OPAD] = (_Float16)acc[nt][i];
        }
    }
}

// ---------------- output: gather F=40 (fp16, stride OPAD) + log_softmax ----
__global__ __launch_bounds__(256) void k_out(const _Float16* __restrict__ XW,
                                             const int* __restrict__ rowp,
                                             const int2* __restrict__ edat,
                                             const float* __restrict__ dinv,
                                             const float* __restrict__ bias,
                                             float* __restrict__ out) {
    const int wave = threadIdx.x >> 6;
    const int lane = threadIdx.x & 63;
    const int node = blockIdx.x * 4 + wave;
    const float dd = dinv[node];
    const bool act = lane < NCLS;
    const int e0 = rowp[node];
    const int deg = rowp[node + 1] - e0;
    int pidx = 0; float pw = 0.f;
    if (lane < deg) {
        const int2 e = edat[e0 + lane];
        pidx = e.x; pw = __int_as_float(e.y);
    }
    const _Float16* Xl = XW + lane;
    float acc = 0.f;
    if (act) acc = dd * dd * (float)Xl[(size_t)node * OPAD];
    auto batch8 = [&](int j0) {
        int bi[8]; float bw[8];
#pragma unroll
        for (int j = 0; j < 8; j++) {
            const int   v  = __shfl(pidx, j0 + j);
            const float wv = __shfl(pw,  j0 + j);
            const bool ok = (j0 + j) < deg;
            bi[j] = ok ? v : node;
            bw[j] = ok ? wv : 0.f;
        }
        if (act) {
            _Float16 v0 = Xl[(size_t)bi[0] * OPAD];
            _Float16 v1 = Xl[(size_t)bi[1] * OPAD];
            _Float16 v2 = Xl[(size_t)bi[2] * OPAD];
            _Float16 v3 = Xl[(size_t)bi[3] * OPAD];
            _Float16 v4 = Xl[(size_t)bi[4] * OPAD];
            _Float16 v5 = Xl[(size_t)bi[5] * OPAD];
            _Float16 v6 = Xl[(size_t)bi[6] * OPAD];
            _Float16 v7 = Xl[(size_t)bi[7] * OPAD];
            asm volatile("" : "+v"(v0), "+v"(v1), "+v"(v2), "+v"(v3),
                              "+v"(v4), "+v"(v5), "+v"(v6), "+v"(v7));
            acc += bw[0] * (float)v0 + bw[1] * (float)v1
                 + bw[2] * (float)v2 + bw[3] * (float)v3
                 + bw[4] * (float)v4 + bw[5] * (float)v5
                 + bw[6] * (float)v6 + bw[7] * (float)v7;
        }
    };
    batch8(0);
    if (deg > 8) {
        batch8(8);
        if (deg > 16) {
            batch8(16);
            if (deg > 24) {
                batch8(24);
                if (deg > 32) {
                    for (int j = 32; j < deg; j++) {
                        const int2 ed = edat[e0 + j];
                        if (act) acc += __int_as_float(ed.y) * (float)Xl[(size_t)ed.x * OPAD];
                    }
                }
            }
        }
    }
    if (act) acc += bias[lane];
    float m = act ? acc : -1e30f;
#pragma unroll
    for (int off = 32; off > 0; off >>= 1) m = fmaxf(m, __shfl_xor(m, off));
    float e = act ? expf(acc - m) : 0.f;
#pragma unroll
    for (int off = 32; off > 0; off >>= 1) e += __shfl_xor(e, off);
    const float lse = m + logf(e);
    if (act) out[node * NCLS + lane] = acc - lse;
}

extern "C" void kernel_launch(void* const* d_in, const int* in_sizes, int n_in,
                              void* d_out, int out_size, void* d_ws, size_t ws_size,
                              hipStream_t stream) {
    const float* x   = (const float*)d_in[0];
    const int*   ei  = (const int*)d_in[1];
    const float* W1  = (const float*)d_in[2];
    const float* b1  = (const float*)d_in[3];
    const float* g1  = (const float*)d_in[4];
    const float* be1 = (const float*)d_in[5];
    const float* W2  = (const float*)d_in[6];
    const float* b2  = (const float*)d_in[7];
    const float* g2  = (const float*)d_in[8];
    const float* be2 = (const float*)d_in[9];
    const float* W3  = (const float*)d_in[10];
    const float* b3  = (const float*)d_in[11];
    float* out = (float*)d_out;

    const int* e_src = ei;
    const int* e_dst = ei + N_EDGES;

    // ---- workspace layout ----
    char* w = (char*)d_ws;
    _Float16* Xh  = (_Float16*)w;              w += (size_t)N_NODES * IN_FEAT * 2;  // 12.8 MB
    _Float16* H1h = (_Float16*)w;              w += (size_t)N_NODES * HIDDEN * 2;   // 25.6 MB
    _Float16* H2h = (_Float16*)w;              w += (size_t)N_NODES * HIDDEN * 2;   // 25.6 MB
    _Float16* XW3h = (_Float16*)w;             w += (size_t)N_NODES * OPAD * 2;     // 6.4 MB
    float* dinv   = (float*)w;                 w += (size_t)N_NODES * 4;
    int2*  edat   = (int2*)w;                  w += (size_t)N_EDGES * 8;            // 2.56 MB
    // --- contiguous zero-init region (single memset) ---
    int*   counts = (int*)w;                   w += (size_t)N_NODES * 4;            // 200000 B
    float* bnp2a  = (float*)w;                 w += (size_t)32 * 512 * 4;           // 64 KB
    float* bnp2b  = (float*)w;                 w += (size_t)32 * 512 * 4;           // 64 KB
    // ---
    int*   rowp   = (int*)w;                   w += (size_t)(N_NODES + 4) * 4;
    int*   cursor = (int*)w;                   w += (size_t)N_NODES * 4;
    int*   partials=(int*)w;                   w += 256 * 4;
    float* scale1 = (float*)w;                 w += 256 * 4;
    float* shift1 = (float*)w;                 w += 256 * 4;
    float* scale2 = (float*)w;                 w += 256 * 4;
    float* shift2 = (float*)w;                 w += 256 * 4;
    _Float16* W1p = (_Float16*)w;              w += (size_t)16 * 4 * 64 * 8 * 2;    // 64 KB
    _Float16* W2p = (_Float16*)w;              w += (size_t)16 * 8 * 64 * 8 * 2;    // 128 KB
    _Float16* W3p = (_Float16*)w;              w += (size_t)3 * 8 * 64 * 8 * 2;     // 24 KB

    const int EB = (N_EDGES + 255) / 256;

    // ---- CSR build + prep (hist fused with cast/pack) ----
    hipMemsetAsync(counts, 0, (size_t)N_NODES * 4 + 2 * (size_t)32 * 512 * 4, stream);
    k_prep<<<PREP_HIST_NB + PREP_CVT_NB + PREP_PACK_NB, 256, 0, stream>>>(
        e_dst, counts, x, Xh, W1, W2, W3, W1p, W2p, W3p);
    k_scan_local<<<SCAN_NB, SCAN_B, 0, stream>>>(counts, rowp, partials);
    k_scan_add<<<SCAN_NB, SCAN_B, 0, stream>>>(rowp, cursor, partials, counts, dinv);
    k_scatter<<<EB, 256, 0, stream>>>(e_src, e_dst, cursor, dinv, edat);

    // ---- layer 1: fused (gather X -> MFMA W1 + b1 -> H1h, stats) ----
    k_fused<IN_FEAT, false><<<GNB, 256, 0, stream>>>(
        Xh, rowp, edat, dinv, nullptr, nullptr, W1p, b1, H1h, bnp2a);
    k_bnprep<<<1, 256, 0, stream>>>(bnp2a, g1, be1, scale1, shift1);

    // ---- layer 2: fused (gather relu(bn(H1)) per-edge -> MFMA W2 -> H2h) ----
    k_fused<HIDDEN, true><<<GNB, 256, 0, stream>>>(
        H1h, rowp, edat, dinv, scale1, shift1, W2p, b2, H2h, bnp2b);
    k_bnprep<<<1, 256, 0, stream>>>(bnp2b, g2, be2, scale2, shift2);

    // ---- output layer ----
    k_gemm3<HIDDEN><<<GNB, 64, 0, stream>>>(H2h, W3p, scale2, shift2, XW3h);
    k_out<<<N_NODES / 4, 256, 0, stream>>>(XW3h, rowp, edat, dinv, b3, out);
}

// Round 11
// 237.729 us; speedup vs baseline: 1.0334x; 1.0199x over previous
//
#include <hip/hip_runtime.h>

#define N_NODES 50000
#define N_EDGES 320000
#define IN_FEAT 128
#define HIDDEN  256
#define NCLS    40
#define OPAD    64                                  // padded out-cols (2 lines)
#define BN_EPS  1e-5f

#define SCAN_B  256
#define SCAN_NB ((N_NODES + SCAN_B - 1) / SCAN_B)   // 196
#define GNB     (N_NODES / 16)                      // 3125 blocks, 16 nodes each

// prep kernel partition
#define PREP_HIST_NB  (N_EDGES / 256)               // 1250
#define PREP_CVT_NB   (N_NODES * IN_FEAT / 8 / 256) // 3125
#define PREP_PACK_NB  54                            // 216 wave-units / 4

typedef __attribute__((ext_vector_type(8))) _Float16 f16x8;
typedef __attribute__((ext_vector_type(2))) _Float16 f16x2;
typedef __attribute__((ext_vector_type(4))) float f32x4;

__device__ __forceinline__ f16x2 pkmax0(f16x2 a) {
    return __builtin_elementwise_max(a, (f16x2)(_Float16)0.f);
}

__device__ __forceinline__ void packB_unit(const float* __restrict__ W,
                                           _Float16* __restrict__ Bp,
                                           int nt, int kt, int nkt, int M, int lane) {
    const int n = nt * 16 + (lane & 15);
    const int kb = kt * 32 + (lane >> 4) * 8;
    _Float16* dst = Bp + (((size_t)nt * nkt + kt) * 64 + lane) * 8;
#pragma unroll
    for (int j = 0; j < 8; j++)
        dst[j] = (n < M) ? (_Float16)W[(size_t)(kb + j) * M + n] : (_Float16)0.f;
}

// ---------------- merged prep: hist + x cast + W packs ----------------
__global__ __launch_bounds__(256) void k_prep(const int* __restrict__ e_dst,
                                              int* __restrict__ counts,
                                              const float* __restrict__ x,
                                              _Float16* __restrict__ Xh,
                                              const float* __restrict__ W1,
                                              const float* __restrict__ W2,
                                              const float* __restrict__ W3,
                                              _Float16* __restrict__ W1p,
                                              _Float16* __restrict__ W2p,
                                              _Float16* __restrict__ W3p) {
    const int b = blockIdx.x;
    const int tid = threadIdx.x;
    if (b < PREP_HIST_NB) {
        const int e = b * 256 + tid;                  // 1250*256 == N_EDGES
        atomicAdd(&counts[e_dst[e]], 1);
    } else if (b < PREP_HIST_NB + PREP_CVT_NB) {
        const int i = (b - PREP_HIST_NB) * 256 + tid; // exact cover
        float4 a = *(const float4*)(x + (size_t)i * 8);
        float4 c = *(const float4*)(x + (size_t)i * 8 + 4);
        f16x8 o = {(_Float16)a.x, (_Float16)a.y, (_Float16)a.z, (_Float16)a.w,
                   (_Float16)c.x, (_Float16)c.y, (_Float16)c.z, (_Float16)c.w};
        *(f16x8*)&Xh[(size_t)i * 8] = o;
    } else {
        const int wave = tid >> 6, lane = tid & 63;
        const int u = (b - PREP_HIST_NB - PREP_CVT_NB) * 4 + wave;  // 0..215
        if (u < 64) {
            packB_unit(W1, W1p, u >> 2, u & 3, 4, HIDDEN, lane);
        } else if (u < 192) {
            const int v = u - 64;
            packB_unit(W2, W2p, v >> 3, v & 7, 8, HIDDEN, lane);
        } else {
            const int v = u - 192;
            packB_unit(W3, W3p, v >> 3, v & 7, 8, NCLS, lane);
        }
    }
}

// ---------------- CSR scan ----------------
__global__ __launch_bounds__(SCAN_B) void k_scan_local(const int* __restrict__ counts,
                                                       int* __restrict__ rowp,
                                                       int* __restrict__ partials) {
    __shared__ int s[SCAN_B];
    const int tid = threadIdx.x;
    const int i = blockIdx.x * SCAN_B + tid;
    int v = (i < N_NODES) ? counts[i] : 0;
    s[tid] = v;
    __syncthreads();
    for (int off = 1; off < SCAN_B; off <<= 1) {
        int t = (tid >= off) ? s[tid - off] : 0;
        __syncthreads();
        s[tid] += t;
        __syncthreads();
    }
    if (i < N_NODES) rowp[i] = s[tid] - v;
    if (tid == SCAN_B - 1) partials[blockIdx.x] = s[SCAN_B - 1];
}

__global__ __launch_bounds__(SCAN_B) void k_scan_add(int* __restrict__ rowp,
                                                     int* __restrict__ cursor,
                                                     const int* __restrict__ partials,
                                                     const int* __restrict__ counts,
                                                     float* __restrict__ dinv) {
    __shared__ int s[SCAN_B];
    const int tid = threadIdx.x;
    const int b = blockIdx.x;
    int v = (tid < b) ? partials[tid] : 0;
    s[tid] = v;
    __syncthreads();
    for (int off = SCAN_B / 2; off > 0; off >>= 1) {
        if (tid < off) s[tid] += s[tid + off];
        __syncthreads();
    }
    const int offset = s[0];
    const int i = b * SCAN_B + tid;
    if (i < N_NODES) {
        int r = rowp[i] + offset;
        rowp[i] = r;
        cursor[i] = r;
        dinv[i] = rsqrtf(1.0f + (float)counts[i]);
    }
    if (b == 0 && tid == 0) rowp[N_NODES] = N_EDGES;
}

// scatter: packed (src, wnorm) per edge -> single 8B random store
__global__ void k_scatter(const int* __restrict__ src, const int* __restrict__ dst,
                          int* __restrict__ cursor, const float* __restrict__ dinv,
                          int2* __restrict__ edat) {
    int e = blockIdx.x * blockDim.x + threadIdx.x;
    if (e < N_EDGES) {
        int d = dst[e], s = src[e];
        int p = atomicAdd(&cursor[d], 1);
        int2 v; v.x = s; v.y = __float_as_int(dinv[s] * dinv[d]);
        edat[p] = v;
    }
}

// ---------------- fused layer: parallel-row gather -> LDS -> MFMA f16 --------
// Block: 16 nodes, 4 per wave via 16-lane subgroups.
// KIN=128 (no BN): asm-batched 16 loads live at once (short 1-FMA tail; R8).
// KIN=256 (BN folded): R1's PREDICATED edge loop — measured best for this
//   shape (46.1 us / 83.3 GB vs dummy-batch8 49.2 / 87.6 and mega-asm 51.5):
//   with a 3-op BN tail per load, predication beats both dummy work and a
//   full-drain schedule; the compiler interleaves vmcnt waits with BN+FMA.
template <int KIN, bool BN>
__global__ __launch_bounds__(256, 4) void k_fused(const _Float16* __restrict__ Xin,
                                                  const int* __restrict__ rowp,
                                                  const int2* __restrict__ edat,
                                                  const float* __restrict__ dinv,
                                                  const float* __restrict__ scale,
                                                  const float* __restrict__ shift,
                                                  const _Float16* __restrict__ Bp,
                                                  const float* __restrict__ bias,
                                                  _Float16* __restrict__ C,
                                                  float* __restrict__ bnp2) {
    constexpr int nkt = KIN / 32;
    constexpr int LROW = KIN + 8;
    constexpr int RW8 = KIN / 8;                 // f16x8 words per feature row
    constexpr int NL = KIN / 128;                // f16x8 loads per lane per row
    __shared__ __align__(16) _Float16 At[16 * LROW];
    const int wave = threadIdx.x >> 6;
    const int lane = threadIdx.x & 63;
    const int sub  = lane >> 4;                  // node slot within wave
    const int t    = lane & 15;                  // lane within subgroup
    const int sb   = lane & 48;                  // subgroup base lane
    const int node = blockIdx.x * 16 + wave * 4 + sub;

    const int e0 = rowp[node];
    const int deg = rowp[node + 1] - e0;
    // coalesced preload of up to 16 (src, w) pairs into the subgroup's lanes
    int   pidx = 0;
    float pw   = 0.f;
    if (t < deg) {
        const int2 e = edat[e0 + t];
        pidx = e.x;
        pw = __int_as_float(e.y);
    }
    const float dd = dinv[node];
    const f16x2 sw2 = (f16x2)(_Float16)(dd * dd);

    // per-lane BN constants for the feature slots this lane covers
    f16x2 scq[NL][4], shq[NL][4];
    if constexpr (BN) {
#pragma unroll
        for (int q = 0; q < NL; q++)
#pragma unroll
            for (int p = 0; p < 4; p++) {
                const int f0 = q * 128 + t * 8 + 2 * p;
                scq[q][p] = f16x2{(_Float16)scale[f0], (_Float16)scale[f0 + 1]};
                shq[q][p] = f16x2{(_Float16)shift[f0], (_Float16)shift[f0 + 1]};
            }
    }

    const f16x8* __restrict__ Xr = (const f16x8*)Xin;
    union U8 { f16x8 v; f16x2 h[4]; };

    U8 a[NL];
#pragma unroll
    for (int q = 0; q < NL; q++) {
        U8 r; r.v = Xr[(size_t)node * RW8 + q * 16 + t];
#pragma unroll
        for (int p = 0; p < 4; p++) {
            f16x2 v = r.h[p];
            if constexpr (BN) v = pkmax0(scq[q][p] * v + shq[q][p]);
            a[q].h[p] = sw2 * v;
        }
    }

    auto proc = [&](U8& r, _Float16 w, int q) {
        const f16x2 w2 = (f16x2)w;
#pragma unroll
        for (int p = 0; p < 4; p++) {
            f16x2 v = r.h[p];
            if constexpr (BN) v = pkmax0(scq[q][p] * v + shq[q][p]);
            a[q].h[p] = w2 * v + a[q].h[p];
        }
    };

    if constexpr (NL == 1) {
        // 16 edges, 16 loads, all live at the single asm point (short tail)
        int bi[16]; _Float16 bw[16];
#pragma unroll
        for (int j = 0; j < 16; j++) {
            const int   v  = __shfl(pidx, sb + j);
            const float wv = __shfl(pw,  sb + j);
            const bool ok = j < deg;
            bi[j] = ok ? v : node;                      // dummy: self row (cache hit)
            bw[j] = ok ? (_Float16)wv : (_Float16)0.f;  // dummy: exact no-op
        }
        U8 r0, r1, r2, r3, r4, r5, r6, r7, r8, r9, r10, r11, r12, r13, r14, r15;
        r0.v  = Xr[(size_t)bi[0]  * RW8 + t];
        r1.v  = Xr[(size_t)bi[1]  * RW8 + t];
        r2.v  = Xr[(size_t)bi[2]  * RW8 + t];
        r3.v  = Xr[(size_t)bi[3]  * RW8 + t];
        r4.v  = Xr[(size_t)bi[4]  * RW8 + t];
        r5.v  = Xr[(size_t)bi[5]  * RW8 + t];
        r6.v  = Xr[(size_t)bi[6]  * RW8 + t];
        r7.v  = Xr[(size_t)bi[7]  * RW8 + t];
        r8.v  = Xr[(size_t)bi[8]  * RW8 + t];
        r9.v  = Xr[(size_t)bi[9]  * RW8 + t];
        r10.v = Xr[(size_t)bi[10] * RW8 + t];
        r11.v = Xr[(size_t)bi[11] * RW8 + t];
        r12.v = Xr[(size_t)bi[12] * RW8 + t];
        r13.v = Xr[(size_t)bi[13] * RW8 + t];
        r14.v = Xr[(size_t)bi[14] * RW8 + t];
        r15.v = Xr[(size_t)bi[15] * RW8 + t];
        asm volatile("" : "+v"(r0.v), "+v"(r1.v), "+v"(r2.v), "+v"(r3.v),
                          "+v"(r4.v), "+v"(r5.v), "+v"(r6.v), "+v"(r7.v),
                          "+v"(r8.v), "+v"(r9.v), "+v"(r10.v), "+v"(r11.v),
                          "+v"(r12.v), "+v"(r13.v), "+v"(r14.v), "+v"(r15.v));
        proc(r0, bw[0], 0);   proc(r1, bw[1], 0);
        proc(r2, bw[2], 0);   proc(r3, bw[3], 0);
        proc(r4, bw[4], 0);   proc(r5, bw[5], 0);
        proc(r6, bw[6], 0);   proc(r7, bw[7], 0);
        proc(r8, bw[8], 0);   proc(r9, bw[9], 0);
        proc(r10, bw[10], 0); proc(r11, bw[11], 0);
        proc(r12, bw[12], 0); proc(r13, bw[13], 0);
        proc(r14, bw[14], 0); proc(r15, bw[15], 0);
    } else {
        // R1's predicated edge loop — no dummy loads, no forced drain
        auto edge = [&](int j) {
            const int   idx = __shfl(pidx, sb + j);
            const float wv  = __shfl(pw,  sb + j);
            if (j < deg) {
                const _Float16 wj = (_Float16)wv;
                U8 r0, r1;
                r0.v = Xr[(size_t)idx * RW8 + t];
                r1.v = Xr[(size_t)idx * RW8 + 16 + t];
                proc(r0, wj, 0);
                proc(r1, wj, 1);
            }
        };
#pragma unroll
        for (int j = 0; j < 8; j++) edge(j);
        if (__any(deg > 8)) {
#pragma unroll
            for (int j = 8; j < 16; j++) edge(j);
        }
    }
    if (__any(deg > 16)) {
        for (int j = 16; j < deg; j++) {
            const int2 ed = edat[e0 + j];
            const _Float16 wj = (_Float16)__int_as_float(ed.y);
#pragma unroll
            for (int q = 0; q < NL; q++) {
                U8 r; r.v = Xr[(size_t)ed.x * RW8 + q * 16 + t];
                proc(r, wj, q);
            }
        }
    }
#pragma unroll
    for (int q = 0; q < NL; q++)
        *(f16x8*)&At[(wave * 4 + sub) * LROW + q * 128 + t * 8] = a[q].v;
    __syncthreads();

    // ---- phase 2: MFMA f16 ----
    const int rowb = blockIdx.x * 16;
    const int ntile0 = wave * 4;
    const _Float16* aL = &At[(lane & 15) * LROW + (lane >> 4) * 8];
    f32x4 acc[4] = {};
#pragma unroll
    for (int kt = 0; kt < nkt; kt++) {
        f16x8 af = *(const f16x8*)(aL + kt * 32);
#pragma unroll
        for (int nt = 0; nt < 4; nt++) {
            f16x8 bfr = *(const f16x8*)(Bp + (((size_t)(ntile0 + nt) * nkt + kt) * 64 + lane) * 8);
            acc[nt] = __builtin_amdgcn_mfma_f32_16x16x32_f16(af, bfr, acc[nt], 0, 0, 0);
        }
    }
    const int rg = lane >> 4, cc = lane & 15;    // C/D: col=lane&15, row=rg*4+i
    float s[4], q2[4];
#pragma unroll
    for (int nt = 0; nt < 4; nt++) {
        const int col = (ntile0 + nt) * 16 + cc;
        const float b = bias[col];
        f32x4 a2 = acc[nt];
        a2[0] += b; a2[1] += b; a2[2] += b; a2[3] += b;
        const size_t base = (size_t)(rowb + rg * 4) * HIDDEN + col;
#pragma unroll
        for (int i = 0; i < 4; i++) C[base + (size_t)i * HIDDEN] = (_Float16)a2[i];
        s[nt] = a2[0] + a2[1] + a2[2] + a2[3];
        q2[nt] = a2[0]*a2[0] + a2[1]*a2[1] + a2[2]*a2[2] + a2[3]*a2[3];
    }
#pragma unroll
    for (int nt = 0; nt < 4; nt++) {
        s[nt] += __shfl_xor(s[nt], 16); s[nt] += __shfl_xor(s[nt], 32);
        q2[nt] += __shfl_xor(q2[nt], 16); q2[nt] += __shfl_xor(q2[nt], 32);
    }
    if (lane < 16) {
        float* dst = bnp2 + ((blockIdx.x & 31) * 512) + ntile0 * 16 + lane;
#pragma unroll
        for (int nt = 0; nt < 4; nt++) {
            atomicAdd(&dst[nt * 16], s[nt]);
            atomicAdd(&dst[nt * 16 + 256], q2[nt]);
        }
    }
}

// ---------------- BN prep: bnp2[32][512] -> scale/shift ----------------
__global__ __launch_bounds__(256) void k_bnprep(const float* __restrict__ bnp2,
                                                const float* __restrict__ g,
                                                const float* __restrict__ be,
                                                float* __restrict__ scale,
                                                float* __restrict__ shift) {
    const int f = threadIdx.x;
    float s = 0.f, q = 0.f;
#pragma unroll
    for (int b = 0; b < 32; b++) {
        s += bnp2[(size_t)b * 512 + f];
        q += bnp2[(size_t)b * 512 + 256 + f];
    }
    const float inv_n = 1.0f / (float)N_NODES;
    float mean = s * inv_n;
    float var = q * inv_n - mean * mean;
    var = fmaxf(var, 0.f);
    float sc = g[f] * rsqrtf(var + BN_EPS);
    scale[f] = sc;
    shift[f] = be[f] - mean * sc;
}

// ---------------- GEMM3: XW3 = relu(bn(H2)) @ W3, fp16 out (stride OPAD) ----
template <int K_>
__global__ __launch_bounds__(64) void k_gemm3(const _Float16* __restrict__ A,
                                              const _Float16* __restrict__ Bp,
                                              const float* __restrict__ scale,
                                              const float* __restrict__ shift,
                                              _Float16* __restrict__ C) {
    constexpr int nkt = K_ / 32;
    constexpr int MT = 3;
    const int lane = threadIdx.x & 63;
    const int rowb = blockIdx.x * 16;
    const int koff = (lane >> 4) * 8;
    const _Float16* aptr = A + (size_t)(rowb + (lane & 15)) * K_ + koff;
    f32x4 acc[MT] = {};
#pragma unroll
    for (int kt = 0; kt < nkt; kt++) {
        union { f16x8 v; f16x2 h[4]; } au, tu;
        au.v = *(const f16x8*)(aptr + kt * 32);
        const int kb = kt * 32 + koff;
#pragma unroll
        for (int p = 0; p < 4; p++) {
            f16x2 sc2 = {(_Float16)scale[kb + 2 * p], (_Float16)scale[kb + 2 * p + 1]};
            f16x2 sh2 = {(_Float16)shift[kb + 2 * p], (_Float16)shift[kb + 2 * p + 1]};
            tu.h[p] = pkmax0(sc2 * au.h[p] + sh2);
        }
#pragma unroll
        for (int nt = 0; nt < MT; nt++) {
            f16x8 bfr = *(const f16x8*)(Bp + (((size_t)nt * nkt + kt) * 64 + lane) * 8);
            acc[nt] = __builtin_amdgcn_mfma_f32_16x16x32_f16(tu.v, bfr, acc[nt], 0, 0, 0);
        }
    }
    const int rg = lane >> 4, cc = lane & 15;
#pragma unroll
    for (int nt = 0; nt < MT; nt++) {
        const int col = nt * 16 + cc;
        if (col < NCLS) {
            const size_t base = (size_t)(rowb + rg * 4) * OPAD + col;
#pragma unroll
            for (int i = 0; i < 4; i++) C[base + (size_t)i * OPAD] = (_Float16)acc[nt][i];
        }
    }
}

// ---------------- output: gather F=40 (fp16, stride OPAD) + log_softmax ----
__global__ __launch_bounds__(256) void k_out(const _Float16* __restrict__ XW,
                                             const int* __restrict__ rowp,
                                             const int2* __restrict__ edat,
                                             const float* __restrict__ dinv,
                                             const float* __restrict__ bias,
                                             float* __restrict__ out) {
    const int wave = threadIdx.x >> 6;
    const int lane = threadIdx.x & 63;
    const int node = blockIdx.x * 4 + wave;
    const float dd = dinv[node];
    const bool act = lane < NCLS;
    const int e0 = rowp[node];
    const int deg = rowp[node + 1] - e0;
    int pidx = 0; float pw = 0.f;
    if (lane < deg) {
        const int2 e = edat[e0 + lane];
        pidx = e.x; pw = __int_as_float(e.y);
    }
    const _Float16* Xl = XW + lane;
    float acc = 0.f;
    if (act) acc = dd * dd * (float)Xl[(size_t)node * OPAD];
    auto batch8 = [&](int j0) {
        int bi[8]; float bw[8];
#pragma unroll
        for (int j = 0; j < 8; j++) {
            const int   v  = __shfl(pidx, j0 + j);
            const float wv = __shfl(pw,  j0 + j);
            const bool ok = (j0 + j) < deg;
            bi[j] = ok ? v : node;
            bw[j] = ok ? wv : 0.f;
        }
        if (act) {
            _Float16 v0 = Xl[(size_t)bi[0] * OPAD];
            _Float16 v1 = Xl[(size_t)bi[1] * OPAD];
            _Float16 v2 = Xl[(size_t)bi[2] * OPAD];
            _Float16 v3 = Xl[(size_t)bi[3] * OPAD];
            _Float16 v4 = Xl[(size_t)bi[4] * OPAD];
            _Float16 v5 = Xl[(size_t)bi[5] * OPAD];
            _Float16 v6 = Xl[(size_t)bi[6] * OPAD];
            _Float16 v7 = Xl[(size_t)bi[7] * OPAD];
            asm volatile("" : "+v"(v0), "+v"(v1), "+v"(v2), "+v"(v3),
                              "+v"(v4), "+v"(v5), "+v"(v6), "+v"(v7));
            acc += bw[0] * (float)v0 + bw[1] * (float)v1
                 + bw[2] * (float)v2 + bw[3] * (float)v3
                 + bw[4] * (float)v4 + bw[5] * (float)v5
                 + bw[6] * (float)v6 + bw[7] * (float)v7;
        }
    };
    batch8(0);
    if (deg > 8) {
        batch8(8);
        if (deg > 16) {
            batch8(16);
            if (deg > 24) {
                batch8(24);
                if (deg > 32) {
                    for (int j = 32; j < deg; j++) {
                        const int2 ed = edat[e0 + j];
                        if (act) acc += __int_as_float(ed.y) * (float)Xl[(size_t)ed.x * OPAD];
                    }
                }
            }
        }
    }
    if (act) acc += bias[lane];
    float m = act ? acc : -1e30f;
#pragma unroll
    for (int off = 32; off > 0; off >>= 1) m = fmaxf(m, __shfl_xor(m, off));
    float e = act ? expf(acc - m) : 0.f;
#pragma unroll
    for (int off = 32; off > 0; off >>= 1) e += __shfl_xor(e, off);
    const float lse = m + logf(e);
    if (act) out[node * NCLS + lane] = acc - lse;
}

extern "C" void kernel_launch(void* const* d_in, const int* in_sizes, int n_in,
                              void* d_out, int out_size, void* d_ws, size_t ws_size,
                              hipStream_t stream) {
    const float* x   = (const float*)d_in[0];
    const int*   ei  = (const int*)d_in[1];
    const float* W1  = (const float*)d_in[2];
    const float* b1  = (const float*)d_in[3];
    const float* g1  = (const float*)d_in[4];
    const float* be1 = (const float*)d_in[5];
    const float* W2  = (const float*)d_in[6];
    const float* b2  = (const float*)d_in[7];
    const float* g2  = (const float*)d_in[8];
    const float* be2 = (const float*)d_in[9];
    const float* W3  = (const float*)d_in[10];
    const float* b3  = (const float*)d_in[11];
    float* out = (float*)d_out;

    const int* e_src = ei;
    const int* e_dst = ei + N_EDGES;

    // ---- workspace layout ----
    char* w = (char*)d_ws;
    _Float16* Xh  = (_Float16*)w;              w += (size_t)N_NODES * IN_FEAT * 2;  // 12.8 MB
    _Float16* H1h = (_Float16*)w;              w += (size_t)N_NODES * HIDDEN * 2;   // 25.6 MB
    _Float16* H2h = (_Float16*)w;              w += (size_t)N_NODES * HIDDEN * 2;   // 25.6 MB
    _Float16* XW3h = (_Float16*)w;             w += (size_t)N_NODES * OPAD * 2;     // 6.4 MB
    float* dinv   = (float*)w;                 w += (size_t)N_NODES * 4;
    int2*  edat   = (int2*)w;                  w += (size_t)N_EDGES * 8;            // 2.56 MB
    // --- contiguous zero-init region (single memset) ---
    int*   counts = (int*)w;                   w += (size_t)N_NODES * 4;            // 200000 B
    float* bnp2a  = (float*)w;                 w += (size_t)32 * 512 * 4;           // 64 KB
    float* bnp2b  = (float*)w;                 w += (size_t)32 * 512 * 4;           // 64 KB
    // ---
    int*   rowp   = (int*)w;                   w += (size_t)(N_NODES + 4) * 4;
    int*   cursor = (int*)w;                   w += (size_t)N_NODES * 4;
    int*   partials=(int*)w;                   w += 256 * 4;
    float* scale1 = (float*)w;                 w += 256 * 4;
    float* shift1 = (float*)w;                 w += 256 * 4;
    float* scale2 = (float*)w;                 w += 256 * 4;
    float* shift2 = (float*)w;                 w += 256 * 4;
    _Float16* W1p = (_Float16*)w;              w += (size_t)16 * 4 * 64 * 8 * 2;    // 64 KB
    _Float16* W2p = (_Float16*)w;              w += (size_t)16 * 8 * 64 * 8 * 2;    // 128 KB
    _Float16* W3p = (_Float16*)w;              w += (size_t)3 * 8 * 64 * 8 * 2;     // 24 KB

    const int EB = (N_EDGES + 255) / 256;

    // ---- CSR build + prep (hist fused with cast/pack) ----
    hipMemsetAsync(counts, 0, (size_t)N_NODES * 4 + 2 * (size_t)32 * 512 * 4, stream);
    k_prep<<<PREP_HIST_NB + PREP_CVT_NB + PREP_PACK_NB, 256, 0, stream>>>(
        e_dst, counts, x, Xh, W1, W2, W3, W1p, W2p, W3p);
    k_scan_local<<<SCAN_NB, SCAN_B, 0, stream>>>(counts, rowp, partials);
    k_scan_add<<<SCAN_NB, SCAN_B, 0, stream>>>(rowp, cursor, partials, counts, dinv);
    k_scatter<<<EB, 256, 0, stream>>>(e_src, e_dst, cursor, dinv, edat);

    // ---- layer 1: fused (gather X -> MFMA W1 + b1 -> H1h, stats) ----
    k_fused<IN_FEAT, false><<<GNB, 256, 0, stream>>>(
        Xh, rowp, edat, dinv, nullptr, nullptr, W1p, b1, H1h, bnp2a);
    k_bnprep<<<1, 256, 0, stream>>>(bnp2a, g1, be1, scale1, shift1);

    // ---- layer 2: fused (gather relu(bn(H1)) per-edge -> MFMA W2 -> H2h) ----
    k_fused<HIDDEN, true><<<GNB, 256, 0, stream>>>(
        H1h, rowp, edat, dinv, scale1, shift1, W2p, b2, H2h, bnp2b);
    k_bnprep<<<1, 256, 0, stream>>>(bnp2b, g2, be2, scale2, shift2);

    // ---- output layer ----
    k_gemm3<HIDDEN><<<GNB, 64, 0, stream>>>(H2h, W3p, scale2, shift2, XW3h);
    k_out<<<N_NODES / 4, 256, 0, stream>>>(XW3h, rowp, edat, dinv, b3, out);
}